// Round 1
// baseline (1998.363 us; speedup 1.0000x reference)
//
#include <hip/hip_runtime.h>
#include <hip/hip_bf16.h>
#include <cstddef>

#define NN 10000      // nodes
#define EE0 160000    // raw edges (self-loops added on top)
#define NF 14
#define DC 256        // per-head channels

static inline int ceildiv(int a, int b) { return (a + b - 1) / b; }

__device__ __forceinline__ float lrelu02(float x) { return fmaxf(x, 0.2f * x); }

// ---------------- CSR build ----------------
__global__ void count_edges_k(const int* __restrict__ ei, int* __restrict__ counts,
                              int E0, int N) {
    int e = blockIdx.x * 256 + threadIdx.x;
    int E = E0 + N;
    if (e >= E) return;
    int dst = (e < E0) ? ei[E0 + e] : (e - E0);
    atomicAdd(&counts[dst], 1);
}

__global__ void scan_k(const int* __restrict__ counts, int* __restrict__ row_off, int n) {
    __shared__ int sh[1024];
    __shared__ int carry_sh;
    int t = threadIdx.x;
    if (t == 0) { carry_sh = 0; row_off[0] = 0; }
    __syncthreads();
    for (int base = 0; base < n; base += 1024) {
        int idx = base + t;
        int v = (idx < n) ? counts[idx] : 0;
        sh[t] = v;
        __syncthreads();
        for (int off = 1; off < 1024; off <<= 1) {
            int add = (t >= off) ? sh[t - off] : 0;
            __syncthreads();
            sh[t] += add;
            __syncthreads();
        }
        if (idx < n) row_off[idx + 1] = carry_sh + sh[t];
        __syncthreads();
        if (t == 0) carry_sh += sh[1023];
        __syncthreads();
    }
}

__global__ void scatter_k(const int* __restrict__ ei, const int* __restrict__ row_off,
                          int* __restrict__ cursor, int* __restrict__ csr_src,
                          int E0, int N) {
    int e = blockIdx.x * 256 + threadIdx.x;
    int E = E0 + N;
    if (e >= E) return;
    int src, dst;
    if (e < E0) { src = ei[e]; dst = ei[E0 + e]; }
    else        { src = dst = e - E0; }
    int pos = row_off[dst] + atomicAdd(&cursor[dst], 1);
    csr_src[pos] = src;
}

// ---------------- GEMMs: C[M,N] = A[M,K] @ W[N,K]^T (+ b1 + b2) ----------------
// Small-K path (layer 1, K=14)
__global__ __launch_bounds__(256) void gemm_smallk(
    const float* __restrict__ A, const float* __restrict__ W,
    const float* __restrict__ b1, const float* __restrict__ b2,
    float* __restrict__ C, int M, int N, int K) {
    int n = blockIdx.x * 256 + threadIdx.x;
    int m = blockIdx.y;
    if (n >= N || m >= M) return;
    const float* a = A + (size_t)m * K;
    const float* w = W + (size_t)n * K;
    float s = 0.f;
    for (int k = 0; k < K; ++k) s += a[k] * w[k];
    if (b1) s += b1[n] + b2[n];
    C[(size_t)m * N + n] = s;
}

// Tiled fp32 GEMM, 128x128 tile, BK=8, 256 threads, 8x8 per thread. K%8==0, N%128==0.
__global__ __launch_bounds__(256) void gemm_k1024(
    const float* __restrict__ A, const float* __restrict__ W,
    const float* __restrict__ b1, const float* __restrict__ b2,
    float* __restrict__ C, int M, int N, int K) {
    __shared__ float As[8][128];
    __shared__ float Bs[8][128];
    const int t = threadIdx.x;
    const int m0 = blockIdx.y * 128;
    const int n0 = blockIdx.x * 128;
    const int lr = t >> 1;          // 0..127 tile row for loading
    const int lc = (t & 1) * 4;     // k quad
    const int tx = t & 15;          // col group (8 cols)
    const int ty = t >> 4;          // row group (8 rows)

    float acc[8][8];
#pragma unroll
    for (int i = 0; i < 8; ++i)
#pragma unroll
        for (int j = 0; j < 8; ++j) acc[i][j] = 0.f;

    int am = m0 + lr; if (am > M - 1) am = M - 1;   // clamp (stores guarded)
    const float* aptr = A + (size_t)am * K + lc;
    const float* bptr = W + (size_t)(n0 + lr) * K + lc;

    for (int k0 = 0; k0 < K; k0 += 8) {
        float4 av = *(const float4*)(aptr + k0);
        float4 bv = *(const float4*)(bptr + k0);
        As[lc + 0][lr] = av.x; As[lc + 1][lr] = av.y;
        As[lc + 2][lr] = av.z; As[lc + 3][lr] = av.w;
        Bs[lc + 0][lr] = bv.x; Bs[lc + 1][lr] = bv.y;
        Bs[lc + 2][lr] = bv.z; Bs[lc + 3][lr] = bv.w;
        __syncthreads();
#pragma unroll
        for (int kk = 0; kk < 8; ++kk) {
            float a[8], b[8];
#pragma unroll
            for (int i = 0; i < 8; ++i) a[i] = As[kk][ty * 8 + i];
#pragma unroll
            for (int j = 0; j < 8; ++j) b[j] = Bs[kk][tx * 8 + j];
#pragma unroll
            for (int i = 0; i < 8; ++i)
#pragma unroll
                for (int j = 0; j < 8; ++j) acc[i][j] += a[i] * b[j];
        }
        __syncthreads();
    }

#pragma unroll
    for (int i = 0; i < 8; ++i) {
        int m = m0 + ty * 8 + i;
        if (m >= M) continue;
#pragma unroll
        for (int j = 0; j < 8; j += 4) {
            int n = n0 + tx * 8 + j;
            float4 v = make_float4(acc[i][j], acc[i][j + 1], acc[i][j + 2], acc[i][j + 3]);
            if (b1) {
                v.x += b1[n + 0] + b2[n + 0];
                v.y += b1[n + 1] + b2[n + 1];
                v.z += b1[n + 2] + b2[n + 2];
                v.w += b1[n + 3] + b2[n + 3];
            }
            *(float4*)(C + (size_t)m * N + n) = v;
        }
    }
}

// ---------------- alpha_src/alpha_dst: [N,H] dot over C=256 ----------------
__global__ __launch_bounds__(256) void alpha_k(
    const float* __restrict__ h, const float* __restrict__ a_s,
    const float* __restrict__ a_d, float* __restrict__ asrc,
    float* __restrict__ adst, int N, int H) {
    int wid = (int)((blockIdx.x * (size_t)blockDim.x + threadIdx.x) >> 6);
    int lane = threadIdx.x & 63;
    if (wid >= N * H) return;
    int n = wid / H, hh = wid - n * H;
    const float4 hv = *(const float4*)(h + (size_t)n * H * DC + hh * DC + lane * 4);
    const float4 sv = *(const float4*)(a_s + hh * DC + lane * 4);
    const float4 dv = *(const float4*)(a_d + hh * DC + lane * 4);
    float s = hv.x * sv.x + hv.y * sv.y + hv.z * sv.z + hv.w * sv.w;
    float d = hv.x * dv.x + hv.y * dv.y + hv.z * dv.z + hv.w * dv.w;
#pragma unroll
    for (int off = 32; off > 0; off >>= 1) {
        s += __shfl_down(s, off);
        d += __shfl_down(d, off);
    }
    if (lane == 0) { asrc[wid] = s; adst[wid] = d; }
}

// ---------------- GAT aggregation, concat heads, fused lin-skip + ELU ----------------
// one wave per (node, head); outx[n, h*256+c] = act(lin[n,h*256+c] + sum_e coef*h[src])
__global__ __launch_bounds__(256) void gat_agg(
    const float* __restrict__ hbuf, const float* __restrict__ lin,
    const float* __restrict__ asrc, const float* __restrict__ adst_a,
    const int* __restrict__ row_off, const int* __restrict__ csr_src,
    float* __restrict__ outx, int N, int H, int do_elu) {
    int wid = (int)((blockIdx.x * (size_t)blockDim.x + threadIdx.x) >> 6);
    int lane = threadIdx.x & 63;
    if (wid >= N * H) return;
    int n = wid / H, hh = wid - n * H;
    int beg = row_off[n], end = row_off[n + 1];
    float ad = adst_a[wid];

    float m = -1e38f;
    for (int i = beg + lane; i < end; i += 64) {
        int s = csr_src[i];
        m = fmaxf(m, lrelu02(asrc[s * H + hh] + ad));
    }
#pragma unroll
    for (int off = 32; off > 0; off >>= 1) m = fmaxf(m, __shfl_xor(m, off));

    float dsum = 0.f;
    for (int i = beg + lane; i < end; i += 64) {
        int s = csr_src[i];
        dsum += __expf(lrelu02(asrc[s * H + hh] + ad) - m);
    }
#pragma unroll
    for (int off = 32; off > 0; off >>= 1) dsum += __shfl_xor(dsum, off);
    float inv = 1.f / (dsum + 1e-16f);

    size_t cbase = (size_t)n * H * DC + hh * DC + lane * 4;
    float4 acc = *(const float4*)(lin + cbase);
    for (int i = beg; i < end; ++i) {
        int s = csr_src[i];
        float w = __expf(lrelu02(asrc[s * H + hh] + ad) - m) * inv;
        const float4 hv = *(const float4*)(hbuf + (size_t)s * H * DC + hh * DC + lane * 4);
        acc.x += w * hv.x; acc.y += w * hv.y; acc.z += w * hv.z; acc.w += w * hv.w;
    }
    if (do_elu) {
        acc.x = acc.x > 0.f ? acc.x : __expf(acc.x) - 1.f;
        acc.y = acc.y > 0.f ? acc.y : __expf(acc.y) - 1.f;
        acc.z = acc.z > 0.f ? acc.z : __expf(acc.z) - 1.f;
        acc.w = acc.w > 0.f ? acc.w : __expf(acc.w) - 1.f;
    }
    *(float4*)(outx + cbase) = acc;
}

// ---------------- Layer-3 aggregation: mean over heads, write d_out[N,256] ----------------
// one wave per node; out already contains lin3 + b3 + lb3
__global__ __launch_bounds__(256) void gat_agg_mean(
    const float* __restrict__ hbuf, const float* __restrict__ asrc,
    const float* __restrict__ adst_a, const int* __restrict__ row_off,
    const int* __restrict__ csr_src, float* __restrict__ out, int N, int H) {
    int wid = (int)((blockIdx.x * (size_t)blockDim.x + threadIdx.x) >> 6);
    int lane = threadIdx.x & 63;
    if (wid >= N) return;
    int n = wid;
    int beg = row_off[n], end = row_off[n + 1];
    const float invH = 1.f / 6.f;

    float4 acc = *(const float4*)(out + (size_t)n * DC + lane * 4);
    for (int hh = 0; hh < H; ++hh) {
        float ad = adst_a[n * H + hh];
        float m = -1e38f;
        for (int i = beg + lane; i < end; i += 64) {
            int s = csr_src[i];
            m = fmaxf(m, lrelu02(asrc[s * H + hh] + ad));
        }
#pragma unroll
        for (int off = 32; off > 0; off >>= 1) m = fmaxf(m, __shfl_xor(m, off));
        float dsum = 0.f;
        for (int i = beg + lane; i < end; i += 64) {
            int s = csr_src[i];
            dsum += __expf(lrelu02(asrc[s * H + hh] + ad) - m);
        }
#pragma unroll
        for (int off = 32; off > 0; off >>= 1) dsum += __shfl_xor(dsum, off);
        float inv = invH / (dsum + 1e-16f);
        for (int i = beg; i < end; ++i) {
            int s = csr_src[i];
            float w = __expf(lrelu02(asrc[s * H + hh] + ad) - m) * inv;
            const float4 hv = *(const float4*)(hbuf + (size_t)s * H * DC + hh * DC + lane * 4);
            acc.x += w * hv.x; acc.y += w * hv.y; acc.z += w * hv.z; acc.w += w * hv.w;
        }
    }
    *(float4*)(out + (size_t)n * DC + lane * 4) = acc;
}

// ---------------- launch ----------------
extern "C" void kernel_launch(void* const* d_in, const int* in_sizes, int n_in,
                              void* d_out, int out_size, void* d_ws, size_t ws_size,
                              hipStream_t stream) {
    const float* x   = (const float*)d_in[0];
    const int*   ei  = (const int*)d_in[1];
    const float* W1  = (const float*)d_in[2];
    const float* a1s = (const float*)d_in[3];
    const float* a1d = (const float*)d_in[4];
    const float* b1  = (const float*)d_in[5];
    const float* lw1 = (const float*)d_in[6];
    const float* lb1 = (const float*)d_in[7];
    const float* W2  = (const float*)d_in[8];
    const float* a2s = (const float*)d_in[9];
    const float* a2d = (const float*)d_in[10];
    const float* b2  = (const float*)d_in[11];
    const float* lw2 = (const float*)d_in[12];
    const float* lb2 = (const float*)d_in[13];
    const float* W3  = (const float*)d_in[14];
    const float* a3s = (const float*)d_in[15];
    const float* a3d = (const float*)d_in[16];
    const float* b3  = (const float*)d_in[17];
    const float* lw3 = (const float*)d_in[18];
    const float* lb3 = (const float*)d_in[19];
    float* out = (float*)d_out;

    const int N = NN, E0 = EE0, E = EE0 + NN;

    // workspace layout (all 256B-aligned)
    unsigned char* w = (unsigned char*)d_ws;
    size_t off = 0;
    auto alloc = [&](size_t bytes) {
        void* p = w + off;
        off += (bytes + 255) & ~(size_t)255;
        return p;
    };
    float* hbuf  = (float*)alloc((size_t)N * 1536 * 4);  // h (max: layer 3)
    float* bufB  = (float*)alloc((size_t)N * 1024 * 4);  // lin1 -> x1
    float* bufC  = (float*)alloc((size_t)N * 1024 * 4);  // lin2 -> x2
    float* asrc  = (float*)alloc((size_t)N * 6 * 4);
    float* adst  = (float*)alloc((size_t)N * 6 * 4);
    int* row_off = (int*)alloc((size_t)(N + 1) * 4);
    int* counts  = (int*)alloc((size_t)N * 4);
    int* cursor  = (int*)alloc((size_t)N * 4);
    int* csr_src = (int*)alloc((size_t)E * 4);
    (void)ws_size; (void)n_in; (void)in_sizes; (void)out_size;

    // ---- CSR build ----
    hipMemsetAsync(counts, 0, (size_t)N * 4, stream);
    hipMemsetAsync(cursor, 0, (size_t)N * 4, stream);
    count_edges_k<<<ceildiv(E, 256), 256, 0, stream>>>(ei, counts, E0, N);
    scan_k<<<1, 1024, 0, stream>>>(counts, row_off, N);
    scatter_k<<<ceildiv(E, 256), 256, 0, stream>>>(ei, row_off, cursor, csr_src, E0, N);

    // ---- Layer 1 (H=4, K=14) ----
    gemm_smallk<<<dim3(4, N), 256, 0, stream>>>(x, W1, nullptr, nullptr, hbuf, N, 1024, NF);
    gemm_smallk<<<dim3(4, N), 256, 0, stream>>>(x, lw1, b1, lb1, bufB, N, 1024, NF);
    alpha_k<<<ceildiv(N * 4, 4), 256, 0, stream>>>(hbuf, a1s, a1d, asrc, adst, N, 4);
    gat_agg<<<ceildiv(N * 4, 4), 256, 0, stream>>>(hbuf, bufB, asrc, adst, row_off, csr_src,
                                                   bufB, N, 4, 1);

    // ---- Layer 2 (H=4, K=1024) ----
    gemm_k1024<<<dim3(1024 / 128, ceildiv(N, 128)), 256, 0, stream>>>(
        bufB, W2, nullptr, nullptr, hbuf, N, 1024, 1024);
    gemm_k1024<<<dim3(1024 / 128, ceildiv(N, 128)), 256, 0, stream>>>(
        bufB, lw2, b2, lb2, bufC, N, 1024, 1024);
    alpha_k<<<ceildiv(N * 4, 4), 256, 0, stream>>>(hbuf, a2s, a2d, asrc, adst, N, 4);
    gat_agg<<<ceildiv(N * 4, 4), 256, 0, stream>>>(hbuf, bufC, asrc, adst, row_off, csr_src,
                                                   bufC, N, 4, 1);

    // ---- Layer 3 (H=6, K=1024, mean heads) ----
    gemm_k1024<<<dim3(1536 / 128, ceildiv(N, 128)), 256, 0, stream>>>(
        bufC, W3, nullptr, nullptr, hbuf, N, 1536, 1024);
    gemm_k1024<<<dim3(256 / 128, ceildiv(N, 128)), 256, 0, stream>>>(
        bufC, lw3, b3, lb3, out, N, 256, 1024);
    alpha_k<<<ceildiv(N * 6, 4), 256, 0, stream>>>(hbuf, a3s, a3d, asrc, adst, N, 6);
    gat_agg_mean<<<ceildiv(N, 4), 256, 0, stream>>>(hbuf, asrc, adst, row_off, csr_src,
                                                    out, N, 6);
}

// Round 2
// 986.358 us; speedup vs baseline: 2.0260x; 2.0260x over previous
//
#include <hip/hip_runtime.h>
#include <hip/hip_bf16.h>
#include <cstddef>

#define NN 10000      // nodes
#define EE0 160000    // raw edges (self-loops added on top)
#define NF 14
#define DC 256        // per-head channels

static inline int ceildiv(int a, int b) { return (a + b - 1) / b; }

__device__ __forceinline__ float lrelu02(float x) { return fmaxf(x, 0.2f * x); }

// round-to-nearest-even fp32 -> bf16 (as raw short)
__device__ __forceinline__ short f2bf(float f) {
    unsigned u = __float_as_uint(f);
    unsigned r = (u + 0x7FFFu + ((u >> 16) & 1u)) >> 16;
    return (short)r;
}

typedef __attribute__((ext_vector_type(8))) short bf16x8;
typedef __attribute__((ext_vector_type(4))) float f32x4;

#define GLDS(gaddr, laddr)                                                         \
    __builtin_amdgcn_global_load_lds(                                              \
        (__attribute__((address_space(1))) void*)(gaddr),                          \
        (__attribute__((address_space(3))) void*)(laddr), 16, 0, 0)

// ---------------- CSR build ----------------
__global__ void count_edges_k(const int* __restrict__ ei, int* __restrict__ counts,
                              int E0, int N) {
    int e = blockIdx.x * 256 + threadIdx.x;
    int E = E0 + N;
    if (e >= E) return;
    int dst = (e < E0) ? ei[E0 + e] : (e - E0);
    atomicAdd(&counts[dst], 1);
}

__global__ void scan_k(const int* __restrict__ counts, int* __restrict__ row_off, int n) {
    __shared__ int sh[1024];
    __shared__ int carry_sh;
    int t = threadIdx.x;
    if (t == 0) { carry_sh = 0; row_off[0] = 0; }
    __syncthreads();
    for (int base = 0; base < n; base += 1024) {
        int idx = base + t;
        int v = (idx < n) ? counts[idx] : 0;
        sh[t] = v;
        __syncthreads();
        for (int off = 1; off < 1024; off <<= 1) {
            int add = (t >= off) ? sh[t - off] : 0;
            __syncthreads();
            sh[t] += add;
            __syncthreads();
        }
        if (idx < n) row_off[idx + 1] = carry_sh + sh[t];
        __syncthreads();
        if (t == 0) carry_sh += sh[1023];
        __syncthreads();
    }
}

__global__ void scatter_k(const int* __restrict__ ei, const int* __restrict__ row_off,
                          int* __restrict__ cursor, int* __restrict__ csr_src,
                          int E0, int N) {
    int e = blockIdx.x * 256 + threadIdx.x;
    int E = E0 + N;
    if (e >= E) return;
    int src, dst;
    if (e < E0) { src = ei[e]; dst = ei[E0 + e]; }
    else        { src = dst = e - E0; }
    int pos = row_off[dst] + atomicAdd(&cursor[dst], 1);
    csr_src[pos] = src;
}

// ---------------- fp32 -> bf16 weight conversion ----------------
__global__ __launch_bounds__(256) void cvt_bf16_k(const float* __restrict__ in,
                                                  short* __restrict__ out, int n4) {
    int i = blockIdx.x * 256 + threadIdx.x;
    if (i >= n4) return;
    float4 v = ((const float4*)in)[i];
    short4 o;
    o.x = f2bf(v.x); o.y = f2bf(v.y); o.z = f2bf(v.z); o.w = f2bf(v.w);
    ((short4*)out)[i] = o;
}

// ---------------- Small-K fp32 GEMM (layer 1, K=14) ----------------
__global__ __launch_bounds__(256) void gemm_smallk(
    const float* __restrict__ A, const float* __restrict__ W,
    const float* __restrict__ b1, const float* __restrict__ b2,
    float* __restrict__ C, int M, int N, int K) {
    int n = blockIdx.x * 256 + threadIdx.x;
    int m = blockIdx.y;
    if (n >= N || m >= M) return;
    const float* a = A + (size_t)m * K;
    const float* w = W + (size_t)n * K;
    float s = 0.f;
    for (int k = 0; k < K; ++k) s += a[k] * w[k];
    if (b1) s += b1[n] + b2[n];
    C[(size_t)m * N + n] = s;
}

// ---------------- bf16 MFMA GEMM: C[M,N] = A[M,K]@B[N,K]^T (+b1+b2) ----------------
// A,B bf16 (raw shorts) K-contiguous; C fp32. N%128==0, K%32==0. M tail clamped.
// 128x128 tile, BK=32, 256 thr = 4 waves in 2x2, each wave 64x64 via 4x4 of 16x16x32.
__global__ __launch_bounds__(256) void gemm_bf16(
    const short* __restrict__ A, const short* __restrict__ B,
    const float* __restrict__ b1, const float* __restrict__ b2,
    float* __restrict__ C, int M, int N, int K) {
    __shared__ short As[128 * 32];
    __shared__ short Bs[128 * 32];
    const int t = threadIdx.x;
    const int wave = t >> 6, lane = t & 63;
    const int m0 = blockIdx.y * 128, n0 = blockIdx.x * 128;
    const int wm = (wave >> 1) * 64, wn = (wave & 1) * 64;
    const int lane15 = lane & 15, quad = lane >> 4;

    // staging: each wave fills 16 rows (1024B) per pass; 2 passes for 128 rows.
    const int lrow = lane >> 2;        // row within wave region
    const int lk = (lane & 3) * 8;     // k offset in shorts (16B chunks)
    int arow0 = m0 + wave * 16 + lrow;
    int arow1 = arow0 + 64;
    if (arow0 > M - 1) arow0 = M - 1;
    if (arow1 > M - 1) arow1 = M - 1;
    const short* ag0 = A + (size_t)arow0 * K + lk;
    const short* ag1 = A + (size_t)arow1 * K + lk;
    const short* bg0 = B + (size_t)(n0 + wave * 16 + lrow) * K + lk;
    const short* bg1 = B + (size_t)(n0 + 64 + wave * 16 + lrow) * K + lk;
    short* al0 = &As[(wave * 16) * 32];
    short* al1 = &As[(64 + wave * 16) * 32];
    short* bl0 = &Bs[(wave * 16) * 32];
    short* bl1 = &Bs[(64 + wave * 16) * 32];

    f32x4 acc[4][4];
#pragma unroll
    for (int i = 0; i < 4; ++i)
#pragma unroll
        for (int j = 0; j < 4; ++j) acc[i][j] = (f32x4){0.f, 0.f, 0.f, 0.f};

    for (int k0 = 0; k0 < K; k0 += 32) {
        GLDS(ag0 + k0, al0);
        GLDS(ag1 + k0, al1);
        GLDS(bg0 + k0, bl0);
        GLDS(bg1 + k0, bl1);
        __syncthreads();
        bf16x8 af[4], bfr[4];
#pragma unroll
        for (int i = 0; i < 4; ++i)
            af[i] = *(const bf16x8*)&As[(wm + 16 * i + lane15) * 32 + quad * 8];
#pragma unroll
        for (int j = 0; j < 4; ++j)
            bfr[j] = *(const bf16x8*)&Bs[(wn + 16 * j + lane15) * 32 + quad * 8];
#pragma unroll
        for (int i = 0; i < 4; ++i)
#pragma unroll
            for (int j = 0; j < 4; ++j)
                acc[i][j] = __builtin_amdgcn_mfma_f32_16x16x32_bf16(
                    af[i], bfr[j], acc[i][j], 0, 0, 0);
        __syncthreads();
    }

#pragma unroll
    for (int j = 0; j < 4; ++j) {
        int n = n0 + wn + 16 * j + lane15;
        float bias = b1 ? (b1[n] + b2[n]) : 0.f;
#pragma unroll
        for (int i = 0; i < 4; ++i) {
            int mb = m0 + wm + 16 * i + quad * 4;
#pragma unroll
            for (int r = 0; r < 4; ++r) {
                int m = mb + r;
                if (m < M) C[(size_t)m * N + n] = acc[i][j][r] + bias;
            }
        }
    }
}

// ---------------- alpha_src/alpha_dst: [N,H] dot over C=256 ----------------
__global__ __launch_bounds__(256) void alpha_k(
    const float* __restrict__ h, const float* __restrict__ a_s,
    const float* __restrict__ a_d, float* __restrict__ asrc,
    float* __restrict__ adst, int N, int H) {
    int wid = (int)((blockIdx.x * (size_t)blockDim.x + threadIdx.x) >> 6);
    int lane = threadIdx.x & 63;
    if (wid >= N * H) return;
    int n = wid / H, hh = wid - n * H;
    const float4 hv = *(const float4*)(h + (size_t)n * H * DC + hh * DC + lane * 4);
    const float4 sv = *(const float4*)(a_s + hh * DC + lane * 4);
    const float4 dv = *(const float4*)(a_d + hh * DC + lane * 4);
    float s = hv.x * sv.x + hv.y * sv.y + hv.z * sv.z + hv.w * sv.w;
    float d = hv.x * dv.x + hv.y * dv.y + hv.z * dv.z + hv.w * dv.w;
#pragma unroll
    for (int off = 32; off > 0; off >>= 1) {
        s += __shfl_down(s, off);
        d += __shfl_down(d, off);
    }
    if (lane == 0) { asrc[wid] = s; adst[wid] = d; }
}

// ---------------- GAT aggregation, concat heads, fused lin-skip + ELU, bf16 out ----
__global__ __launch_bounds__(256) void gat_agg(
    const float* __restrict__ hbuf, const float* __restrict__ lin,
    const float* __restrict__ asrc, const float* __restrict__ adst_a,
    const int* __restrict__ row_off, const int* __restrict__ csr_src,
    short* __restrict__ outx, int N, int H) {
    int wid = (int)((blockIdx.x * (size_t)blockDim.x + threadIdx.x) >> 6);
    int lane = threadIdx.x & 63;
    if (wid >= N * H) return;
    int n = wid / H, hh = wid - n * H;
    int beg = row_off[n], end = row_off[n + 1];
    float ad = adst_a[wid];

    float m = -1e38f;
    for (int i = beg + lane; i < end; i += 64) {
        int s = csr_src[i];
        m = fmaxf(m, lrelu02(asrc[s * H + hh] + ad));
    }
#pragma unroll
    for (int off = 32; off > 0; off >>= 1) m = fmaxf(m, __shfl_xor(m, off));

    float dsum = 0.f;
    for (int i = beg + lane; i < end; i += 64) {
        int s = csr_src[i];
        dsum += __expf(lrelu02(asrc[s * H + hh] + ad) - m);
    }
#pragma unroll
    for (int off = 32; off > 0; off >>= 1) dsum += __shfl_xor(dsum, off);
    float inv = 1.f / (dsum + 1e-16f);

    size_t cbase = (size_t)n * H * DC + hh * DC + lane * 4;
    float4 acc = *(const float4*)(lin + cbase);
    for (int i = beg; i < end; ++i) {
        int s = csr_src[i];
        float w = __expf(lrelu02(asrc[s * H + hh] + ad) - m) * inv;
        const float4 hv = *(const float4*)(hbuf + (size_t)s * H * DC + hh * DC + lane * 4);
        acc.x += w * hv.x; acc.y += w * hv.y; acc.z += w * hv.z; acc.w += w * hv.w;
    }
    // ELU + bf16
    acc.x = acc.x > 0.f ? acc.x : __expf(acc.x) - 1.f;
    acc.y = acc.y > 0.f ? acc.y : __expf(acc.y) - 1.f;
    acc.z = acc.z > 0.f ? acc.z : __expf(acc.z) - 1.f;
    acc.w = acc.w > 0.f ? acc.w : __expf(acc.w) - 1.f;
    short4 o;
    o.x = f2bf(acc.x); o.y = f2bf(acc.y); o.z = f2bf(acc.z); o.w = f2bf(acc.w);
    *(short4*)(outx + cbase) = o;
}

// ---------------- Layer-3 aggregation: mean over heads, write d_out[N,256] ----------
__global__ __launch_bounds__(256) void gat_agg_mean(
    const float* __restrict__ hbuf, const float* __restrict__ asrc,
    const float* __restrict__ adst_a, const int* __restrict__ row_off,
    const int* __restrict__ csr_src, float* __restrict__ out, int N, int H) {
    int wid = (int)((blockIdx.x * (size_t)blockDim.x + threadIdx.x) >> 6);
    int lane = threadIdx.x & 63;
    if (wid >= N) return;
    int n = wid;
    int beg = row_off[n], end = row_off[n + 1];
    const float invH = 1.f / 6.f;

    float4 acc = *(const float4*)(out + (size_t)n * DC + lane * 4);
    for (int hh = 0; hh < H; ++hh) {
        float ad = adst_a[n * H + hh];
        float m = -1e38f;
        for (int i = beg + lane; i < end; i += 64) {
            int s = csr_src[i];
            m = fmaxf(m, lrelu02(asrc[s * H + hh] + ad));
        }
#pragma unroll
        for (int off = 32; off > 0; off >>= 1) m = fmaxf(m, __shfl_xor(m, off));
        float dsum = 0.f;
        for (int i = beg + lane; i < end; i += 64) {
            int s = csr_src[i];
            dsum += __expf(lrelu02(asrc[s * H + hh] + ad) - m);
        }
#pragma unroll
        for (int off = 32; off > 0; off >>= 1) dsum += __shfl_xor(dsum, off);
        float inv = invH / (dsum + 1e-16f);
        for (int i = beg; i < end; ++i) {
            int s = csr_src[i];
            float w = __expf(lrelu02(asrc[s * H + hh] + ad) - m) * inv;
            const float4 hv = *(const float4*)(hbuf + (size_t)s * H * DC + hh * DC + lane * 4);
            acc.x += w * hv.x; acc.y += w * hv.y; acc.z += w * hv.z; acc.w += w * hv.w;
        }
    }
    *(float4*)(out + (size_t)n * DC + lane * 4) = acc;
}

// ---------------- launch ----------------
extern "C" void kernel_launch(void* const* d_in, const int* in_sizes, int n_in,
                              void* d_out, int out_size, void* d_ws, size_t ws_size,
                              hipStream_t stream) {
    const float* x   = (const float*)d_in[0];
    const int*   ei  = (const int*)d_in[1];
    const float* W1  = (const float*)d_in[2];
    const float* a1s = (const float*)d_in[3];
    const float* a1d = (const float*)d_in[4];
    const float* b1  = (const float*)d_in[5];
    const float* lw1 = (const float*)d_in[6];
    const float* lb1 = (const float*)d_in[7];
    const float* W2  = (const float*)d_in[8];
    const float* a2s = (const float*)d_in[9];
    const float* a2d = (const float*)d_in[10];
    const float* b2  = (const float*)d_in[11];
    const float* lw2 = (const float*)d_in[12];
    const float* lb2 = (const float*)d_in[13];
    const float* W3  = (const float*)d_in[14];
    const float* a3s = (const float*)d_in[15];
    const float* a3d = (const float*)d_in[16];
    const float* b3  = (const float*)d_in[17];
    const float* lw3 = (const float*)d_in[18];
    const float* lb3 = (const float*)d_in[19];
    float* out = (float*)d_out;

    const int N = NN, E0 = EE0, E = EE0 + NN;

    unsigned char* w = (unsigned char*)d_ws;
    size_t off = 0;
    auto alloc = [&](size_t bytes) {
        void* p = w + off;
        off += (bytes + 255) & ~(size_t)255;
        return p;
    };
    float* hbuf  = (float*)alloc((size_t)N * 1536 * 4);  // h (max: layer 3)
    float* buf   = (float*)alloc((size_t)N * 1024 * 4);  // lin1, then lin2
    short* xb    = (short*)alloc((size_t)N * 1024 * 2);  // x1 bf16, then x2 bf16
    short* W2b   = (short*)alloc((size_t)1024 * 1024 * 2);
    short* lw2b  = (short*)alloc((size_t)1024 * 1024 * 2);
    short* W3b   = (short*)alloc((size_t)1536 * 1024 * 2);
    short* lw3b  = (short*)alloc((size_t)256 * 1024 * 2);
    float* asrc  = (float*)alloc((size_t)N * 6 * 4);
    float* adst  = (float*)alloc((size_t)N * 6 * 4);
    int* row_off = (int*)alloc((size_t)(N + 1) * 4);
    int* counts  = (int*)alloc((size_t)N * 4);
    int* cursor  = (int*)alloc((size_t)N * 4);
    int* csr_src = (int*)alloc((size_t)E * 4);
    (void)ws_size; (void)n_in; (void)in_sizes; (void)out_size;

    // ---- CSR build ----
    hipMemsetAsync(counts, 0, (size_t)N * 4, stream);
    hipMemsetAsync(cursor, 0, (size_t)N * 4, stream);
    count_edges_k<<<ceildiv(E, 256), 256, 0, stream>>>(ei, counts, E0, N);
    scan_k<<<1, 1024, 0, stream>>>(counts, row_off, N);
    scatter_k<<<ceildiv(E, 256), 256, 0, stream>>>(ei, row_off, cursor, csr_src, E0, N);

    // ---- weight bf16 conversion ----
    cvt_bf16_k<<<ceildiv(1024 * 1024 / 4, 256), 256, 0, stream>>>(W2, W2b, 1024 * 1024 / 4);
    cvt_bf16_k<<<ceildiv(1024 * 1024 / 4, 256), 256, 0, stream>>>(lw2, lw2b, 1024 * 1024 / 4);
    cvt_bf16_k<<<ceildiv(1536 * 1024 / 4, 256), 256, 0, stream>>>(W3, W3b, 1536 * 1024 / 4);
    cvt_bf16_k<<<ceildiv(256 * 1024 / 4, 256), 256, 0, stream>>>(lw3, lw3b, 256 * 1024 / 4);

    // ---- Layer 1 (H=4, K=14, fp32) ----
    gemm_smallk<<<dim3(4, N), 256, 0, stream>>>(x, W1, nullptr, nullptr, hbuf, N, 1024, NF);
    gemm_smallk<<<dim3(4, N), 256, 0, stream>>>(x, lw1, b1, lb1, buf, N, 1024, NF);
    alpha_k<<<ceildiv(N * 4, 4), 256, 0, stream>>>(hbuf, a1s, a1d, asrc, adst, N, 4);
    gat_agg<<<ceildiv(N * 4, 4), 256, 0, stream>>>(hbuf, buf, asrc, adst, row_off, csr_src,
                                                   xb, N, 4);

    // ---- Layer 2 (H=4, K=1024, bf16 MFMA) ----
    gemm_bf16<<<dim3(8, ceildiv(N, 128)), 256, 0, stream>>>(
        xb, W2b, nullptr, nullptr, hbuf, N, 1024, 1024);
    gemm_bf16<<<dim3(8, ceildiv(N, 128)), 256, 0, stream>>>(
        xb, lw2b, b2, lb2, buf, N, 1024, 1024);
    alpha_k<<<ceildiv(N * 4, 4), 256, 0, stream>>>(hbuf, a2s, a2d, asrc, adst, N, 4);
    gat_agg<<<ceildiv(N * 4, 4), 256, 0, stream>>>(hbuf, buf, asrc, adst, row_off, csr_src,
                                                   xb, N, 4);

    // ---- Layer 3 (H=6, K=1024, mean heads) ----
    gemm_bf16<<<dim3(12, ceildiv(N, 128)), 256, 0, stream>>>(
        xb, W3b, nullptr, nullptr, hbuf, N, 1536, 1024);
    gemm_bf16<<<dim3(2, ceildiv(N, 128)), 256, 0, stream>>>(
        xb, lw3b, b3, lb3, out, N, 256, 1024);
    alpha_k<<<ceildiv(N * 6, 4), 256, 0, stream>>>(hbuf, a3s, a3d, asrc, adst, N, 6);
    gat_agg_mean<<<ceildiv(N, 4), 256, 0, stream>>>(hbuf, asrc, adst, row_off, csr_src,
                                                    out, N, 6);
}

// Round 3
// 784.101 us; speedup vs baseline: 2.5486x; 1.2579x over previous
//
#include <hip/hip_runtime.h>
#include <hip/hip_bf16.h>
#include <cstddef>

#define NN 10000      // nodes
#define EE0 160000    // raw edges (self-loops added on top)
#define NF 14
#define DC 256        // per-head channels

static inline int ceildiv(int a, int b) { return (a + b - 1) / b; }

__device__ __forceinline__ float lrelu02(float x) { return fmaxf(x, 0.2f * x); }

// round-to-nearest-even fp32 -> bf16 (as raw short)
__device__ __forceinline__ short f2bf(float f) {
    unsigned u = __float_as_uint(f);
    unsigned r = (u + 0x7FFFu + ((u >> 16) & 1u)) >> 16;
    return (short)r;
}
__device__ __forceinline__ float bf2f(short s) {
    return __uint_as_float(((unsigned)(unsigned short)s) << 16);
}

typedef __attribute__((ext_vector_type(8))) short bf16x8;
typedef __attribute__((ext_vector_type(4))) float f32x4;

#define GLDS(gaddr, laddr)                                                         \
    __builtin_amdgcn_global_load_lds(                                              \
        (__attribute__((address_space(1))) void*)(gaddr),                          \
        (__attribute__((address_space(3))) void*)(laddr), 16, 0, 0)

// ---------------- CSR build ----------------
__global__ void count_edges_k(const int* __restrict__ ei, int* __restrict__ counts,
                              int E0, int N) {
    int e = blockIdx.x * 256 + threadIdx.x;
    int E = E0 + N;
    if (e >= E) return;
    int dst = (e < E0) ? ei[E0 + e] : (e - E0);
    atomicAdd(&counts[dst], 1);
}

__global__ void scan_k(const int* __restrict__ counts, int* __restrict__ row_off, int n) {
    __shared__ int sh[1024];
    __shared__ int carry_sh;
    int t = threadIdx.x;
    if (t == 0) { carry_sh = 0; row_off[0] = 0; }
    __syncthreads();
    for (int base = 0; base < n; base += 1024) {
        int idx = base + t;
        int v = (idx < n) ? counts[idx] : 0;
        sh[t] = v;
        __syncthreads();
        for (int off = 1; off < 1024; off <<= 1) {
            int add = (t >= off) ? sh[t - off] : 0;
            __syncthreads();
            sh[t] += add;
            __syncthreads();
        }
        if (idx < n) row_off[idx + 1] = carry_sh + sh[t];
        __syncthreads();
        if (t == 0) carry_sh += sh[1023];
        __syncthreads();
    }
}

__global__ void scatter_k(const int* __restrict__ ei, const int* __restrict__ row_off,
                          int* __restrict__ cursor, int* __restrict__ csr_src,
                          int E0, int N) {
    int e = blockIdx.x * 256 + threadIdx.x;
    int E = E0 + N;
    if (e >= E) return;
    int src, dst;
    if (e < E0) { src = ei[e]; dst = ei[E0 + e]; }
    else        { src = dst = e - E0; }
    int pos = row_off[dst] + atomicAdd(&cursor[dst], 1);
    csr_src[pos] = src;
}

// ---------------- fused fp32 -> bf16 weight conversion (4 segments) ----------------
__global__ __launch_bounds__(256) void cvt_bf16_fused_k(
    const float* __restrict__ p0, short* __restrict__ q0, int n0,
    const float* __restrict__ p1, short* __restrict__ q1, int n1,
    const float* __restrict__ p2, short* __restrict__ q2, int n2,
    const float* __restrict__ p3, short* __restrict__ q3, int n3) {
    int i = blockIdx.x * 256 + threadIdx.x;
    const float* in; short* out; int idx;
    if (i < n0) { in = p0; out = q0; idx = i; }
    else if (i < n0 + n1) { in = p1; out = q1; idx = i - n0; }
    else if (i < n0 + n1 + n2) { in = p2; out = q2; idx = i - n0 - n1; }
    else if (i < n0 + n1 + n2 + n3) { in = p3; out = q3; idx = i - n0 - n1 - n2; }
    else return;
    float4 v = ((const float4*)in)[idx];
    short4 o;
    o.x = f2bf(v.x); o.y = f2bf(v.y); o.z = f2bf(v.z); o.w = f2bf(v.w);
    ((short4*)out)[idx] = o;
}

// ---------------- Small-K fp32 GEMM (layer 1, K=14) ----------------
// writes fp32 Cf if outb==0, else bf16 Cb
__global__ __launch_bounds__(256) void gemm_smallk(
    const float* __restrict__ A, const float* __restrict__ W,
    const float* __restrict__ b1, const float* __restrict__ b2,
    float* __restrict__ Cf, short* __restrict__ Cb, int M, int N, int K) {
    int n = blockIdx.x * 256 + threadIdx.x;
    int m = blockIdx.y;
    if (n >= N || m >= M) return;
    const float* a = A + (size_t)m * K;
    const float* w = W + (size_t)n * K;
    float s = 0.f;
    for (int k = 0; k < K; ++k) s += a[k] * w[k];
    if (b1) s += b1[n] + b2[n];
    if (Cb) Cb[(size_t)m * N + n] = f2bf(s);
    else    Cf[(size_t)m * N + n] = s;
}

// ---------------- bf16 MFMA GEMM: C[M,N] = A[M,K]@B[N,K]^T (+b1+b2) ----------------
// A,B bf16 (raw shorts) K-contiguous. N%128==0, K%32==0. M tail clamped.
// out: fp32 Cf if Cb==0, else bf16 Cb.
__global__ __launch_bounds__(256) void gemm_bf16(
    const short* __restrict__ A, const short* __restrict__ B,
    const float* __restrict__ b1, const float* __restrict__ b2,
    float* __restrict__ Cf, short* __restrict__ Cb, int M, int N, int K) {
    __shared__ short As[128 * 32];
    __shared__ short Bs[128 * 32];
    const int t = threadIdx.x;
    const int wave = t >> 6, lane = t & 63;
    const int m0 = blockIdx.y * 128, n0 = blockIdx.x * 128;
    const int wm = (wave >> 1) * 64, wn = (wave & 1) * 64;
    const int lane15 = lane & 15, quad = lane >> 4;

    const int lrow = lane >> 2;        // row within wave region
    const int lk = (lane & 3) * 8;     // k offset in shorts (16B chunks)
    int arow0 = m0 + wave * 16 + lrow;
    int arow1 = arow0 + 64;
    if (arow0 > M - 1) arow0 = M - 1;
    if (arow1 > M - 1) arow1 = M - 1;
    const short* ag0 = A + (size_t)arow0 * K + lk;
    const short* ag1 = A + (size_t)arow1 * K + lk;
    const short* bg0 = B + (size_t)(n0 + wave * 16 + lrow) * K + lk;
    const short* bg1 = B + (size_t)(n0 + 64 + wave * 16 + lrow) * K + lk;
    short* al0 = &As[(wave * 16) * 32];
    short* al1 = &As[(64 + wave * 16) * 32];
    short* bl0 = &Bs[(wave * 16) * 32];
    short* bl1 = &Bs[(64 + wave * 16) * 32];

    f32x4 acc[4][4];
#pragma unroll
    for (int i = 0; i < 4; ++i)
#pragma unroll
        for (int j = 0; j < 4; ++j) acc[i][j] = (f32x4){0.f, 0.f, 0.f, 0.f};

    for (int k0 = 0; k0 < K; k0 += 32) {
        GLDS(ag0 + k0, al0);
        GLDS(ag1 + k0, al1);
        GLDS(bg0 + k0, bl0);
        GLDS(bg1 + k0, bl1);
        __syncthreads();
        bf16x8 af[4], bfr[4];
#pragma unroll
        for (int i = 0; i < 4; ++i)
            af[i] = *(const bf16x8*)&As[(wm + 16 * i + lane15) * 32 + quad * 8];
#pragma unroll
        for (int j = 0; j < 4; ++j)
            bfr[j] = *(const bf16x8*)&Bs[(wn + 16 * j + lane15) * 32 + quad * 8];
#pragma unroll
        for (int i = 0; i < 4; ++i)
#pragma unroll
            for (int j = 0; j < 4; ++j)
                acc[i][j] = __builtin_amdgcn_mfma_f32_16x16x32_bf16(
                    af[i], bfr[j], acc[i][j], 0, 0, 0);
        __syncthreads();
    }

#pragma unroll
    for (int j = 0; j < 4; ++j) {
        int n = n0 + wn + 16 * j + lane15;
        float bias = b1 ? (b1[n] + b2[n]) : 0.f;
#pragma unroll
        for (int i = 0; i < 4; ++i) {
            int mb = m0 + wm + 16 * i + quad * 4;
#pragma unroll
            for (int r = 0; r < 4; ++r) {
                int m = mb + r;
                if (m < M) {
                    float v = acc[i][j][r] + bias;
                    if (Cb) Cb[(size_t)m * N + n] = f2bf(v);
                    else    Cf[(size_t)m * N + n] = v;
                }
            }
        }
    }
}

// ---------------- alpha_src/alpha_dst: [N,H] dot over C=256, bf16 h ----------------
__global__ __launch_bounds__(256) void alpha_k(
    const short* __restrict__ h, const float* __restrict__ a_s,
    const float* __restrict__ a_d, float* __restrict__ asrc,
    float* __restrict__ adst, int N, int H) {
    int wid = (int)((blockIdx.x * (size_t)blockDim.x + threadIdx.x) >> 6);
    int lane = threadIdx.x & 63;
    if (wid >= N * H) return;
    int n = wid / H, hh = wid - n * H;
    const short4 hv4 = *(const short4*)(h + (size_t)n * H * DC + hh * DC + lane * 4);
    const float4 sv = *(const float4*)(a_s + hh * DC + lane * 4);
    const float4 dv = *(const float4*)(a_d + hh * DC + lane * 4);
    float hx = bf2f(hv4.x), hy = bf2f(hv4.y), hz = bf2f(hv4.z), hw = bf2f(hv4.w);
    float s = hx * sv.x + hy * sv.y + hz * sv.z + hw * sv.w;
    float d = hx * dv.x + hy * dv.y + hz * dv.z + hw * dv.w;
#pragma unroll
    for (int off = 32; off > 0; off >>= 1) {
        s += __shfl_down(s, off);
        d += __shfl_down(d, off);
    }
    if (lane == 0) { asrc[wid] = s; adst[wid] = d; }
}

// ---------------- GAT aggregation, concat heads, fused lin-skip + ELU, bf16 out ----
// one wave per (node, head); fast path deg<=64 keeps edges in registers.
__global__ __launch_bounds__(256) void gat_agg(
    const short* __restrict__ hbuf, const float* __restrict__ lin,
    const float* __restrict__ asrc, const float* __restrict__ adst_a,
    const int* __restrict__ row_off, const int* __restrict__ csr_src,
    short* __restrict__ outx, int N, int H) {
    int wid = (int)((blockIdx.x * (size_t)blockDim.x + threadIdx.x) >> 6);
    int lane = threadIdx.x & 63;
    if (wid >= N * H) return;
    int n = wid / H, hh = wid - n * H;
    int beg = row_off[n], end = row_off[n + 1];
    int deg = end - beg;
    float ad = adst_a[wid];

    size_t cbase = (size_t)n * H * DC + hh * DC + lane * 4;
    float4 acc = *(const float4*)(lin + cbase);

    if (deg <= 64) {
        int s = 0; float e = -1e38f;
        if (lane < deg) {
            s = csr_src[beg + lane];
            e = lrelu02(asrc[s * H + hh] + ad);
        }
        float m = e;
#pragma unroll
        for (int off = 32; off > 0; off >>= 1) m = fmaxf(m, __shfl_xor(m, off));
        float p = (lane < deg) ? __expf(e - m) : 0.f;
        float dsum = p;
#pragma unroll
        for (int off = 32; off > 0; off >>= 1) dsum += __shfl_xor(dsum, off);
        float coef = p / (dsum + 1e-16f);
        for (int i = 0; i < deg; ++i) {
            float wv = __shfl(coef, i);
            int si = __shfl(s, i);
            const short4 hv = *(const short4*)(hbuf + ((size_t)si * H + hh) * DC + lane * 4);
            acc.x += wv * bf2f(hv.x); acc.y += wv * bf2f(hv.y);
            acc.z += wv * bf2f(hv.z); acc.w += wv * bf2f(hv.w);
        }
    } else {
        float m = -1e38f;
        for (int i = beg + lane; i < end; i += 64) {
            int s = csr_src[i];
            m = fmaxf(m, lrelu02(asrc[s * H + hh] + ad));
        }
#pragma unroll
        for (int off = 32; off > 0; off >>= 1) m = fmaxf(m, __shfl_xor(m, off));
        float dsum = 0.f;
        for (int i = beg + lane; i < end; i += 64) {
            int s = csr_src[i];
            dsum += __expf(lrelu02(asrc[s * H + hh] + ad) - m);
        }
#pragma unroll
        for (int off = 32; off > 0; off >>= 1) dsum += __shfl_xor(dsum, off);
        float inv = 1.f / (dsum + 1e-16f);
        for (int i = beg; i < end; ++i) {
            int s = csr_src[i];
            float wv = __expf(lrelu02(asrc[s * H + hh] + ad) - m) * inv;
            const short4 hv = *(const short4*)(hbuf + ((size_t)s * H + hh) * DC + lane * 4);
            acc.x += wv * bf2f(hv.x); acc.y += wv * bf2f(hv.y);
            acc.z += wv * bf2f(hv.z); acc.w += wv * bf2f(hv.w);
        }
    }
    // ELU + bf16
    acc.x = acc.x > 0.f ? acc.x : __expf(acc.x) - 1.f;
    acc.y = acc.y > 0.f ? acc.y : __expf(acc.y) - 1.f;
    acc.z = acc.z > 0.f ? acc.z : __expf(acc.z) - 1.f;
    acc.w = acc.w > 0.f ? acc.w : __expf(acc.w) - 1.f;
    short4 o;
    o.x = f2bf(acc.x); o.y = f2bf(acc.y); o.z = f2bf(acc.z); o.w = f2bf(acc.w);
    *(short4*)(outx + cbase) = o;
}

// ---------------- Layer-3 aggregation: mean over 6 heads, write d_out[N,256] -------
// one wave per node; out already contains lin3 + b3 + lb3
__global__ __launch_bounds__(256) void gat_agg_mean(
    const short* __restrict__ hbuf, const float* __restrict__ asrc,
    const float* __restrict__ adst_a, const int* __restrict__ row_off,
    const int* __restrict__ csr_src, float* __restrict__ out, int N) {
    const int H = 6;
    int wid = (int)((blockIdx.x * (size_t)blockDim.x + threadIdx.x) >> 6);
    int lane = threadIdx.x & 63;
    if (wid >= N) return;
    int n = wid;
    int beg = row_off[n], end = row_off[n + 1];
    int deg = end - beg;
    const float invH = 1.f / 6.f;

    float4 acc = *(const float4*)(out + (size_t)n * DC + lane * 4);

    if (deg <= 64) {
        int s = 0;
        float as6[6];
        if (lane < deg) {
            s = csr_src[beg + lane];
            const float2* ap = (const float2*)(asrc + (size_t)s * H);
            float2 v0 = ap[0], v1 = ap[1], v2 = ap[2];
            as6[0] = v0.x; as6[1] = v0.y; as6[2] = v1.x;
            as6[3] = v1.y; as6[4] = v2.x; as6[5] = v2.y;
        }
        float coefh[6];
#pragma unroll
        for (int hh = 0; hh < 6; ++hh) {
            float ad = adst_a[n * H + hh];
            float e = (lane < deg) ? lrelu02(as6[hh] + ad) : -1e38f;
            float m = e;
#pragma unroll
            for (int off = 32; off > 0; off >>= 1) m = fmaxf(m, __shfl_xor(m, off));
            float p = (lane < deg) ? __expf(e - m) : 0.f;
            float dsum = p;
#pragma unroll
            for (int off = 32; off > 0; off >>= 1) dsum += __shfl_xor(dsum, off);
            coefh[hh] = p * invH / (dsum + 1e-16f);
        }
        for (int i = 0; i < deg; ++i) {
            int si = __shfl(s, i);
            const short* hb = hbuf + (size_t)si * (H * DC) + lane * 4;
#pragma unroll
            for (int hh = 0; hh < 6; ++hh) {
                float wv = __shfl(coefh[hh], i);
                const short4 hv = *(const short4*)(hb + hh * DC);
                acc.x += wv * bf2f(hv.x); acc.y += wv * bf2f(hv.y);
                acc.z += wv * bf2f(hv.z); acc.w += wv * bf2f(hv.w);
            }
        }
    } else {
        for (int hh = 0; hh < 6; ++hh) {
            float ad = adst_a[n * H + hh];
            float m = -1e38f;
            for (int i = beg + lane; i < end; i += 64) {
                int s = csr_src[i];
                m = fmaxf(m, lrelu02(asrc[s * H + hh] + ad));
            }
#pragma unroll
            for (int off = 32; off > 0; off >>= 1) m = fmaxf(m, __shfl_xor(m, off));
            float dsum = 0.f;
            for (int i = beg + lane; i < end; i += 64) {
                int s = csr_src[i];
                dsum += __expf(lrelu02(asrc[s * H + hh] + ad) - m);
            }
#pragma unroll
            for (int off = 32; off > 0; off >>= 1) dsum += __shfl_xor(dsum, off);
            float inv = invH / (dsum + 1e-16f);
            for (int i = beg; i < end; ++i) {
                int s = csr_src[i];
                float wv = __expf(lrelu02(asrc[s * H + hh] + ad) - m) * inv;
                const short4 hv =
                    *(const short4*)(hbuf + (size_t)s * (H * DC) + hh * DC + lane * 4);
                acc.x += wv * bf2f(hv.x); acc.y += wv * bf2f(hv.y);
                acc.z += wv * bf2f(hv.z); acc.w += wv * bf2f(hv.w);
            }
        }
    }
    *(float4*)(out + (size_t)n * DC + lane * 4) = acc;
}

// ---------------- launch ----------------
extern "C" void kernel_launch(void* const* d_in, const int* in_sizes, int n_in,
                              void* d_out, int out_size, void* d_ws, size_t ws_size,
                              hipStream_t stream) {
    const float* x   = (const float*)d_in[0];
    const int*   ei  = (const int*)d_in[1];
    const float* W1  = (const float*)d_in[2];
    const float* a1s = (const float*)d_in[3];
    const float* a1d = (const float*)d_in[4];
    const float* b1  = (const float*)d_in[5];
    const float* lw1 = (const float*)d_in[6];
    const float* lb1 = (const float*)d_in[7];
    const float* W2  = (const float*)d_in[8];
    const float* a2s = (const float*)d_in[9];
    const float* a2d = (const float*)d_in[10];
    const float* b2  = (const float*)d_in[11];
    const float* lw2 = (const float*)d_in[12];
    const float* lb2 = (const float*)d_in[13];
    const float* W3  = (const float*)d_in[14];
    const float* a3s = (const float*)d_in[15];
    const float* a3d = (const float*)d_in[16];
    const float* b3  = (const float*)d_in[17];
    const float* lw3 = (const float*)d_in[18];
    const float* lb3 = (const float*)d_in[19];
    float* out = (float*)d_out;

    const int N = NN, E0 = EE0, E = EE0 + NN;

    unsigned char* w = (unsigned char*)d_ws;
    size_t off = 0;
    auto alloc = [&](size_t bytes) {
        void* p = w + off;
        off += (bytes + 255) & ~(size_t)255;
        return p;
    };
    short* hbuf  = (short*)alloc((size_t)N * 1536 * 2);  // h bf16 (max: layer 3)
    float* buf   = (float*)alloc((size_t)N * 1024 * 4);  // lin1, then lin2 (fp32)
    short* xb    = (short*)alloc((size_t)N * 1024 * 2);  // x1 bf16, then x2 bf16
    short* W2b   = (short*)alloc((size_t)1024 * 1024 * 2);
    short* lw2b  = (short*)alloc((size_t)1024 * 1024 * 2);
    short* W3b   = (short*)alloc((size_t)1536 * 1024 * 2);
    short* lw3b  = (short*)alloc((size_t)256 * 1024 * 2);
    float* asrc  = (float*)alloc((size_t)N * 6 * 4);
    float* adst  = (float*)alloc((size_t)N * 6 * 4);
    int* row_off = (int*)alloc((size_t)(N + 1) * 4);
    int* counts  = (int*)alloc((size_t)N * 4);
    int* cursor  = (int*)alloc((size_t)N * 4);
    int* csr_src = (int*)alloc((size_t)E * 4);
    (void)ws_size; (void)n_in; (void)in_sizes; (void)out_size;

    // ---- CSR build ----
    hipMemsetAsync(counts, 0, (size_t)N * 4, stream);
    hipMemsetAsync(cursor, 0, (size_t)N * 4, stream);
    count_edges_k<<<ceildiv(E, 256), 256, 0, stream>>>(ei, counts, E0, N);
    scan_k<<<1, 1024, 0, stream>>>(counts, row_off, N);
    scatter_k<<<ceildiv(E, 256), 256, 0, stream>>>(ei, row_off, cursor, csr_src, E0, N);

    // ---- weight bf16 conversion (fused) ----
    {
        int q0 = 1024 * 1024 / 4, q1 = 1024 * 1024 / 4, q2 = 1536 * 1024 / 4,
            q3 = 256 * 1024 / 4;
        cvt_bf16_fused_k<<<ceildiv(q0 + q1 + q2 + q3, 256), 256, 0, stream>>>(
            W2, W2b, q0, lw2, lw2b, q1, W3, W3b, q2, lw3, lw3b, q3);
    }

    // ---- Layer 1 (H=4, K=14, fp32 in; h out bf16) ----
    gemm_smallk<<<dim3(4, N), 256, 0, stream>>>(x, W1, nullptr, nullptr,
                                                nullptr, hbuf, N, 1024, NF);
    gemm_smallk<<<dim3(4, N), 256, 0, stream>>>(x, lw1, b1, lb1,
                                                buf, nullptr, N, 1024, NF);
    alpha_k<<<ceildiv(N * 4, 4), 256, 0, stream>>>(hbuf, a1s, a1d, asrc, adst, N, 4);
    gat_agg<<<ceildiv(N * 4, 4), 256, 0, stream>>>(hbuf, buf, asrc, adst, row_off, csr_src,
                                                   xb, N, 4);

    // ---- Layer 2 (H=4, K=1024, bf16 MFMA) ----
    gemm_bf16<<<dim3(8, ceildiv(N, 128)), 256, 0, stream>>>(
        xb, W2b, nullptr, nullptr, nullptr, hbuf, N, 1024, 1024);
    gemm_bf16<<<dim3(8, ceildiv(N, 128)), 256, 0, stream>>>(
        xb, lw2b, b2, lb2, buf, nullptr, N, 1024, 1024);
    alpha_k<<<ceildiv(N * 4, 4), 256, 0, stream>>>(hbuf, a2s, a2d, asrc, adst, N, 4);
    gat_agg<<<ceildiv(N * 4, 4), 256, 0, stream>>>(hbuf, buf, asrc, adst, row_off, csr_src,
                                                   xb, N, 4);

    // ---- Layer 3 (H=6, K=1024, mean heads) ----
    gemm_bf16<<<dim3(12, ceildiv(N, 128)), 256, 0, stream>>>(
        xb, W3b, nullptr, nullptr, nullptr, hbuf, N, 1536, 1024);
    gemm_bf16<<<dim3(2, ceildiv(N, 128)), 256, 0, stream>>>(
        xb, lw3b, b3, lb3, out, nullptr, N, 256, 1024);
    alpha_k<<<ceildiv(N * 6, 4), 256, 0, stream>>>(hbuf, a3s, a3d, asrc, adst, N, 6);
    gat_agg_mean<<<ceildiv(N, 4), 256, 0, stream>>>(hbuf, asrc, adst, row_off, csr_src,
                                                    out, N);
}

// Round 4
// 558.504 us; speedup vs baseline: 3.5781x; 1.4039x over previous
//
#include <hip/hip_runtime.h>
#include <hip/hip_bf16.h>
#include <cstddef>

#define NN 10000      // nodes
#define EE0 160000    // raw edges (self-loops added on top)
#define NF 14
#define DC 256        // per-head channels

static inline int ceildiv(int a, int b) { return (a + b - 1) / b; }

__device__ __forceinline__ float lrelu02(float x) { return fmaxf(x, 0.2f * x); }

// round-to-nearest-even fp32 -> bf16 (as raw short)
__device__ __forceinline__ short f2bf(float f) {
    unsigned u = __float_as_uint(f);
    unsigned r = (u + 0x7FFFu + ((u >> 16) & 1u)) >> 16;
    return (short)r;
}
__device__ __forceinline__ float bf2f(short s) {
    return __uint_as_float(((unsigned)(unsigned short)s) << 16);
}

typedef __attribute__((ext_vector_type(8))) short bf16x8;
typedef __attribute__((ext_vector_type(4))) float f32x4;

#define GLDS(gaddr, laddr)                                                         \
    __builtin_amdgcn_global_load_lds(                                              \
        (__attribute__((address_space(1))) void*)(gaddr),                          \
        (__attribute__((address_space(3))) void*)(laddr), 16, 0, 0)

// ---------------- CSR build ----------------
__global__ void count_edges_k(const int* __restrict__ ei, int* __restrict__ counts,
                              int E0, int N) {
    int e = blockIdx.x * 256 + threadIdx.x;
    int E = E0 + N;
    if (e >= E) return;
    int dst = (e < E0) ? ei[E0 + e] : (e - E0);
    atomicAdd(&counts[dst], 1);
}

__global__ void scan_k(const int* __restrict__ counts, int* __restrict__ row_off, int n) {
    __shared__ int sh[1024];
    __shared__ int carry_sh;
    int t = threadIdx.x;
    if (t == 0) { carry_sh = 0; row_off[0] = 0; }
    __syncthreads();
    for (int base = 0; base < n; base += 1024) {
        int idx = base + t;
        int v = (idx < n) ? counts[idx] : 0;
        sh[t] = v;
        __syncthreads();
        for (int off = 1; off < 1024; off <<= 1) {
            int add = (t >= off) ? sh[t - off] : 0;
            __syncthreads();
            sh[t] += add;
            __syncthreads();
        }
        if (idx < n) row_off[idx + 1] = carry_sh + sh[t];
        __syncthreads();
        if (t == 0) carry_sh += sh[1023];
        __syncthreads();
    }
}

__global__ void scatter_k(const int* __restrict__ ei, const int* __restrict__ row_off,
                          int* __restrict__ cursor, int* __restrict__ csr_src,
                          int E0, int N) {
    int e = blockIdx.x * 256 + threadIdx.x;
    int E = E0 + N;
    if (e >= E) return;
    int src, dst;
    if (e < E0) { src = ei[e]; dst = ei[E0 + e]; }
    else        { src = dst = e - E0; }
    int pos = row_off[dst] + atomicAdd(&cursor[dst], 1);
    csr_src[pos] = src;
}

// ---------------- fused fp32 -> bf16 weight conversion (4 segments) ----------------
__global__ __launch_bounds__(256) void cvt_bf16_fused_k(
    const float* __restrict__ p0, short* __restrict__ q0, int n0,
    const float* __restrict__ p1, short* __restrict__ q1, int n1,
    const float* __restrict__ p2, short* __restrict__ q2, int n2,
    const float* __restrict__ p3, short* __restrict__ q3, int n3) {
    int i = blockIdx.x * 256 + threadIdx.x;
    const float* in; short* out; int idx;
    if (i < n0) { in = p0; out = q0; idx = i; }
    else if (i < n0 + n1) { in = p1; out = q1; idx = i - n0; }
    else if (i < n0 + n1 + n2) { in = p2; out = q2; idx = i - n0 - n1; }
    else if (i < n0 + n1 + n2 + n3) { in = p3; out = q3; idx = i - n0 - n1 - n2; }
    else return;
    float4 v = ((const float4*)in)[idx];
    short4 o;
    o.x = f2bf(v.x); o.y = f2bf(v.y); o.z = f2bf(v.z); o.w = f2bf(v.w);
    ((short4*)out)[idx] = o;
}

// ---------------- K-pad fp32 [rows,K] -> bf16 [rows,Kp] (zero tail), 3 segments ----
__global__ __launch_bounds__(256) void pad_bf16_k(
    const float* __restrict__ p0, short* __restrict__ q0, int r0,
    const float* __restrict__ p1, short* __restrict__ q1, int r1,
    const float* __restrict__ p2, short* __restrict__ q2, int r2,
    int K, int Kp) {
    int i = blockIdx.x * 256 + threadIdx.x;
    int rows = r0 + r1 + r2;
    int total = rows * Kp;
    if (i >= total) return;
    int row = i / Kp, col = i - row * Kp;
    const float* in; short* out; int r;
    if (row < r0) { in = p0; out = q0; r = row; }
    else if (row < r0 + r1) { in = p1; out = q1; r = row - r0; }
    else { in = p2; out = q2; r = row - r0 - r1; }
    out[(size_t)r * Kp + col] = (col < K) ? f2bf(in[(size_t)r * K + col]) : (short)0;
}

// ---------------- bf16 MFMA GEMM: C[M,N] = A[M,K]@B[N,K]^T (+b1+b2) ----------------
// A,B bf16 (raw shorts) K-contiguous. N%128==0, K%32==0. M tail clamped.
// out: fp32 Cf if Cb==0, else bf16 Cb.
__global__ __launch_bounds__(256) void gemm_bf16(
    const short* __restrict__ A, const short* __restrict__ B,
    const float* __restrict__ b1, const float* __restrict__ b2,
    float* __restrict__ Cf, short* __restrict__ Cb, int M, int N, int K) {
    __shared__ short As[128 * 32];
    __shared__ short Bs[128 * 32];
    const int t = threadIdx.x;
    const int wave = t >> 6, lane = t & 63;
    const int m0 = blockIdx.y * 128, n0 = blockIdx.x * 128;
    const int wm = (wave >> 1) * 64, wn = (wave & 1) * 64;
    const int lane15 = lane & 15, quad = lane >> 4;

    const int lrow = lane >> 2;        // row within wave region
    const int lk = (lane & 3) * 8;     // k offset in shorts (16B chunks)
    int arow0 = m0 + wave * 16 + lrow;
    int arow1 = arow0 + 64;
    if (arow0 > M - 1) arow0 = M - 1;
    if (arow1 > M - 1) arow1 = M - 1;
    const short* ag0 = A + (size_t)arow0 * K + lk;
    const short* ag1 = A + (size_t)arow1 * K + lk;
    const short* bg0 = B + (size_t)(n0 + wave * 16 + lrow) * K + lk;
    const short* bg1 = B + (size_t)(n0 + 64 + wave * 16 + lrow) * K + lk;
    short* al0 = &As[(wave * 16) * 32];
    short* al1 = &As[(64 + wave * 16) * 32];
    short* bl0 = &Bs[(wave * 16) * 32];
    short* bl1 = &Bs[(64 + wave * 16) * 32];

    f32x4 acc[4][4];
#pragma unroll
    for (int i = 0; i < 4; ++i)
#pragma unroll
        for (int j = 0; j < 4; ++j) acc[i][j] = (f32x4){0.f, 0.f, 0.f, 0.f};

    for (int k0 = 0; k0 < K; k0 += 32) {
        GLDS(ag0 + k0, al0);
        GLDS(ag1 + k0, al1);
        GLDS(bg0 + k0, bl0);
        GLDS(bg1 + k0, bl1);
        __syncthreads();
        bf16x8 af[4], bfr[4];
#pragma unroll
        for (int i = 0; i < 4; ++i)
            af[i] = *(const bf16x8*)&As[(wm + 16 * i + lane15) * 32 + quad * 8];
#pragma unroll
        for (int j = 0; j < 4; ++j)
            bfr[j] = *(const bf16x8*)&Bs[(wn + 16 * j + lane15) * 32 + quad * 8];
#pragma unroll
        for (int i = 0; i < 4; ++i)
#pragma unroll
            for (int j = 0; j < 4; ++j)
                acc[i][j] = __builtin_amdgcn_mfma_f32_16x16x32_bf16(
                    af[i], bfr[j], acc[i][j], 0, 0, 0);
        __syncthreads();
    }

#pragma unroll
    for (int j = 0; j < 4; ++j) {
        int n = n0 + wn + 16 * j + lane15;
        float bias = b1 ? (b1[n] + b2[n]) : 0.f;
#pragma unroll
        for (int i = 0; i < 4; ++i) {
            int mb = m0 + wm + 16 * i + quad * 4;
#pragma unroll
            for (int r = 0; r < 4; ++r) {
                int m = mb + r;
                if (m < M) {
                    float v = acc[i][j][r] + bias;
                    if (Cb) Cb[(size_t)m * N + n] = f2bf(v);
                    else    Cf[(size_t)m * N + n] = v;
                }
            }
        }
    }
}

// ---------------- alpha_src/alpha_dst: [N,H] dot over C=256, bf16 h ----------------
__global__ __launch_bounds__(256) void alpha_k(
    const short* __restrict__ h, const float* __restrict__ a_s,
    const float* __restrict__ a_d, float* __restrict__ asrc,
    float* __restrict__ adst, int N, int H) {
    int wid = (int)((blockIdx.x * (size_t)blockDim.x + threadIdx.x) >> 6);
    int lane = threadIdx.x & 63;
    if (wid >= N * H) return;
    int n = wid / H, hh = wid - n * H;
    const short4 hv4 = *(const short4*)(h + (size_t)n * H * DC + hh * DC + lane * 4);
    const float4 sv = *(const float4*)(a_s + hh * DC + lane * 4);
    const float4 dv = *(const float4*)(a_d + hh * DC + lane * 4);
    float hx = bf2f(hv4.x), hy = bf2f(hv4.y), hz = bf2f(hv4.z), hw = bf2f(hv4.w);
    float s = hx * sv.x + hy * sv.y + hz * sv.z + hw * sv.w;
    float d = hx * dv.x + hy * dv.y + hz * dv.z + hw * dv.w;
#pragma unroll
    for (int off = 32; off > 0; off >>= 1) {
        s += __shfl_down(s, off);
        d += __shfl_down(d, off);
    }
    if (lane == 0) { asrc[wid] = s; adst[wid] = d; }
}

// ---------------- GAT aggregation, concat heads, fused lin-skip + ELU, bf16 out ----
// one wave per (node, head); fast path deg<=64 keeps edges in registers.
__global__ __launch_bounds__(256) void gat_agg(
    const short* __restrict__ hbuf, const float* __restrict__ lin,
    const float* __restrict__ asrc, const float* __restrict__ adst_a,
    const int* __restrict__ row_off, const int* __restrict__ csr_src,
    short* __restrict__ outx, int N, int H) {
    int wid = (int)((blockIdx.x * (size_t)blockDim.x + threadIdx.x) >> 6);
    int lane = threadIdx.x & 63;
    if (wid >= N * H) return;
    int n = wid / H, hh = wid - n * H;
    int beg = row_off[n], end = row_off[n + 1];
    int deg = end - beg;
    float ad = adst_a[wid];

    size_t cbase = (size_t)n * H * DC + hh * DC + lane * 4;
    float4 acc = *(const float4*)(lin + cbase);

    if (deg <= 64) {
        int s = 0; float e = -1e38f;
        if (lane < deg) {
            s = csr_src[beg + lane];
            e = lrelu02(asrc[s * H + hh] + ad);
        }
        float m = e;
#pragma unroll
        for (int off = 32; off > 0; off >>= 1) m = fmaxf(m, __shfl_xor(m, off));
        float p = (lane < deg) ? __expf(e - m) : 0.f;
        float dsum = p;
#pragma unroll
        for (int off = 32; off > 0; off >>= 1) dsum += __shfl_xor(dsum, off);
        float coef = p / (dsum + 1e-16f);
        for (int i = 0; i < deg; ++i) {
            float wv = __shfl(coef, i);
            int si = __shfl(s, i);
            const short4 hv = *(const short4*)(hbuf + ((size_t)si * H + hh) * DC + lane * 4);
            acc.x += wv * bf2f(hv.x); acc.y += wv * bf2f(hv.y);
            acc.z += wv * bf2f(hv.z); acc.w += wv * bf2f(hv.w);
        }
    } else {
        float m = -1e38f;
        for (int i = beg + lane; i < end; i += 64) {
            int s = csr_src[i];
            m = fmaxf(m, lrelu02(asrc[s * H + hh] + ad));
        }
#pragma unroll
        for (int off = 32; off > 0; off >>= 1) m = fmaxf(m, __shfl_xor(m, off));
        float dsum = 0.f;
        for (int i = beg + lane; i < end; i += 64) {
            int s = csr_src[i];
            dsum += __expf(lrelu02(asrc[s * H + hh] + ad) - m);
        }
#pragma unroll
        for (int off = 32; off > 0; off >>= 1) dsum += __shfl_xor(dsum, off);
        float inv = 1.f / (dsum + 1e-16f);
        for (int i = beg; i < end; ++i) {
            int s = csr_src[i];
            float wv = __expf(lrelu02(asrc[s * H + hh] + ad) - m) * inv;
            const short4 hv = *(const short4*)(hbuf + ((size_t)s * H + hh) * DC + lane * 4);
            acc.x += wv * bf2f(hv.x); acc.y += wv * bf2f(hv.y);
            acc.z += wv * bf2f(hv.z); acc.w += wv * bf2f(hv.w);
        }
    }
    // ELU + bf16
    acc.x = acc.x > 0.f ? acc.x : __expf(acc.x) - 1.f;
    acc.y = acc.y > 0.f ? acc.y : __expf(acc.y) - 1.f;
    acc.z = acc.z > 0.f ? acc.z : __expf(acc.z) - 1.f;
    acc.w = acc.w > 0.f ? acc.w : __expf(acc.w) - 1.f;
    short4 o;
    o.x = f2bf(acc.x); o.y = f2bf(acc.y); o.z = f2bf(acc.z); o.w = f2bf(acc.w);
    *(short4*)(outx + cbase) = o;
}

// ---------------- Layer-3 aggregation: mean over 6 heads, write d_out[N,256] -------
// one wave per node; out already contains lin3 + b3 + lb3
__global__ __launch_bounds__(256) void gat_agg_mean(
    const short* __restrict__ hbuf, const float* __restrict__ asrc,
    const float* __restrict__ adst_a, const int* __restrict__ row_off,
    const int* __restrict__ csr_src, float* __restrict__ out, int N) {
    const int H = 6;
    int wid = (int)((blockIdx.x * (size_t)blockDim.x + threadIdx.x) >> 6);
    int lane = threadIdx.x & 63;
    if (wid >= N) return;
    int n = wid;
    int beg = row_off[n], end = row_off[n + 1];
    int deg = end - beg;
    const float invH = 1.f / 6.f;

    float4 acc = *(const float4*)(out + (size_t)n * DC + lane * 4);

    if (deg <= 64) {
        int s = 0;
        float as6[6];
        if (lane < deg) {
            s = csr_src[beg + lane];
            const float2* ap = (const float2*)(asrc + (size_t)s * H);
            float2 v0 = ap[0], v1 = ap[1], v2 = ap[2];
            as6[0] = v0.x; as6[1] = v0.y; as6[2] = v1.x;
            as6[3] = v1.y; as6[4] = v2.x; as6[5] = v2.y;
        }
        float coefh[6];
#pragma unroll
        for (int hh = 0; hh < 6; ++hh) {
            float ad = adst_a[n * H + hh];
            float e = (lane < deg) ? lrelu02(as6[hh] + ad) : -1e38f;
            float m = e;
#pragma unroll
            for (int off = 32; off > 0; off >>= 1) m = fmaxf(m, __shfl_xor(m, off));
            float p = (lane < deg) ? __expf(e - m) : 0.f;
            float dsum = p;
#pragma unroll
            for (int off = 32; off > 0; off >>= 1) dsum += __shfl_xor(dsum, off);
            coefh[hh] = p * invH / (dsum + 1e-16f);
        }
        for (int i = 0; i < deg; ++i) {
            int si = __shfl(s, i);
            const short* hb = hbuf + (size_t)si * (H * DC) + lane * 4;
#pragma unroll
            for (int hh = 0; hh < 6; ++hh) {
                float wv = __shfl(coefh[hh], i);
                const short4 hv = *(const short4*)(hb + hh * DC);
                acc.x += wv * bf2f(hv.x); acc.y += wv * bf2f(hv.y);
                acc.z += wv * bf2f(hv.z); acc.w += wv * bf2f(hv.w);
            }
        }
    } else {
        for (int hh = 0; hh < 6; ++hh) {
            float ad = adst_a[n * H + hh];
            float m = -1e38f;
            for (int i = beg + lane; i < end; i += 64) {
                int s = csr_src[i];
                m = fmaxf(m, lrelu02(asrc[s * H + hh] + ad));
            }
#pragma unroll
            for (int off = 32; off > 0; off >>= 1) m = fmaxf(m, __shfl_xor(m, off));
            float dsum = 0.f;
            for (int i = beg + lane; i < end; i += 64) {
                int s = csr_src[i];
                dsum += __expf(lrelu02(asrc[s * H + hh] + ad) - m);
            }
#pragma unroll
            for (int off = 32; off > 0; off >>= 1) dsum += __shfl_xor(dsum, off);
            float inv = invH / (dsum + 1e-16f);
            for (int i = beg; i < end; ++i) {
                int s = csr_src[i];
                float wv = __expf(lrelu02(asrc[s * H + hh] + ad) - m) * inv;
                const short4 hv =
                    *(const short4*)(hbuf + (size_t)s * (H * DC) + hh * DC + lane * 4);
                acc.x += wv * bf2f(hv.x); acc.y += wv * bf2f(hv.y);
                acc.z += wv * bf2f(hv.z); acc.w += wv * bf2f(hv.w);
            }
        }
    }
    *(float4*)(out + (size_t)n * DC + lane * 4) = acc;
}

// ---------------- launch ----------------
extern "C" void kernel_launch(void* const* d_in, const int* in_sizes, int n_in,
                              void* d_out, int out_size, void* d_ws, size_t ws_size,
                              hipStream_t stream) {
    const float* x   = (const float*)d_in[0];
    const int*   ei  = (const int*)d_in[1];
    const float* W1  = (const float*)d_in[2];
    const float* a1s = (const float*)d_in[3];
    const float* a1d = (const float*)d_in[4];
    const float* b1  = (const float*)d_in[5];
    const float* lw1 = (const float*)d_in[6];
    const float* lb1 = (const float*)d_in[7];
    const float* W2  = (const float*)d_in[8];
    const float* a2s = (const float*)d_in[9];
    const float* a2d = (const float*)d_in[10];
    const float* b2  = (const float*)d_in[11];
    const float* lw2 = (const float*)d_in[12];
    const float* lb2 = (const float*)d_in[13];
    const float* W3  = (const float*)d_in[14];
    const float* a3s = (const float*)d_in[15];
    const float* a3d = (const float*)d_in[16];
    const float* b3  = (const float*)d_in[17];
    const float* lw3 = (const float*)d_in[18];
    const float* lb3 = (const float*)d_in[19];
    float* out = (float*)d_out;

    const int N = NN, E0 = EE0, E = EE0 + NN;

    unsigned char* w = (unsigned char*)d_ws;
    size_t off = 0;
    auto alloc = [&](size_t bytes) {
        void* p = w + off;
        off += (bytes + 255) & ~(size_t)255;
        return p;
    };
    short* hbuf  = (short*)alloc((size_t)N * 1536 * 2);  // h bf16 (max: layer 3)
    float* buf   = (float*)alloc((size_t)N * 1024 * 4);  // lin1, then lin2 (fp32)
    short* xb    = (short*)alloc((size_t)N * 1024 * 2);  // x1 bf16, then x2 bf16
    short* xpad  = (short*)alloc((size_t)N * 32 * 2);    // x zero-padded K=32 bf16
    short* W1p   = (short*)alloc((size_t)1024 * 32 * 2);
    short* lw1p  = (short*)alloc((size_t)1024 * 32 * 2);
    short* W2b   = (short*)alloc((size_t)1024 * 1024 * 2);
    short* lw2b  = (short*)alloc((size_t)1024 * 1024 * 2);
    short* W3b   = (short*)alloc((size_t)1536 * 1024 * 2);
    short* lw3b  = (short*)alloc((size_t)256 * 1024 * 2);
    float* asrc  = (float*)alloc((size_t)N * 6 * 4);
    float* adst  = (float*)alloc((size_t)N * 6 * 4);
    int* row_off = (int*)alloc((size_t)(N + 1) * 4);
    int* counts  = (int*)alloc((size_t)N * 4);
    int* cursor  = (int*)alloc((size_t)N * 4);
    int* csr_src = (int*)alloc((size_t)E * 4);
    (void)ws_size; (void)n_in; (void)in_sizes; (void)out_size;

    // ---- CSR build ----
    hipMemsetAsync(counts, 0, (size_t)N * 4, stream);
    hipMemsetAsync(cursor, 0, (size_t)N * 4, stream);
    count_edges_k<<<ceildiv(E, 256), 256, 0, stream>>>(ei, counts, E0, N);
    scan_k<<<1, 1024, 0, stream>>>(counts, row_off, N);
    scatter_k<<<ceildiv(E, 256), 256, 0, stream>>>(ei, row_off, cursor, csr_src, E0, N);

    // ---- weight bf16 conversion (fused) + K-pad for layer 1 ----
    {
        int q0 = 1024 * 1024 / 4, q1 = 1024 * 1024 / 4, q2 = 1536 * 1024 / 4,
            q3 = 256 * 1024 / 4;
        cvt_bf16_fused_k<<<ceildiv(q0 + q1 + q2 + q3, 256), 256, 0, stream>>>(
            W2, W2b, q0, lw2, lw2b, q1, W3, W3b, q2, lw3, lw3b, q3);
        int rows = N + 1024 + 1024;
        pad_bf16_k<<<ceildiv(rows * 32, 256), 256, 0, stream>>>(
            x, xpad, N, W1, W1p, 1024, lw1, lw1p, 1024, NF, 32);
    }

    // ---- Layer 1 (H=4, K=14 padded to 32, bf16 MFMA) ----
    gemm_bf16<<<dim3(8, ceildiv(N, 128)), 256, 0, stream>>>(
        xpad, W1p, nullptr, nullptr, nullptr, hbuf, N, 1024, 32);
    gemm_bf16<<<dim3(8, ceildiv(N, 128)), 256, 0, stream>>>(
        xpad, lw1p, b1, lb1, buf, nullptr, N, 1024, 32);
    alpha_k<<<ceildiv(N * 4, 4), 256, 0, stream>>>(hbuf, a1s, a1d, asrc, adst, N, 4);
    gat_agg<<<ceildiv(N * 4, 4), 256, 0, stream>>>(hbuf, buf, asrc, adst, row_off, csr_src,
                                                   xb, N, 4);

    // ---- Layer 2 (H=4, K=1024, bf16 MFMA) ----
    gemm_bf16<<<dim3(8, ceildiv(N, 128)), 256, 0, stream>>>(
        xb, W2b, nullptr, nullptr, nullptr, hbuf, N, 1024, 1024);
    gemm_bf16<<<dim3(8, ceildiv(N, 128)), 256, 0, stream>>>(
        xb, lw2b, b2, lb2, buf, nullptr, N, 1024, 1024);
    alpha_k<<<ceildiv(N * 4, 4), 256, 0, stream>>>(hbuf, a2s, a2d, asrc, adst, N, 4);
    gat_agg<<<ceildiv(N * 4, 4), 256, 0, stream>>>(hbuf, buf, asrc, adst, row_off, csr_src,
                                                   xb, N, 4);

    // ---- Layer 3 (H=6, K=1024, mean heads) ----
    gemm_bf16<<<dim3(12, ceildiv(N, 128)), 256, 0, stream>>>(
        xb, W3b, nullptr, nullptr, nullptr, hbuf, N, 1536, 1024);
    gemm_bf16<<<dim3(2, ceildiv(N, 128)), 256, 0, stream>>>(
        xb, lw3b, b3, lb3, out, nullptr, N, 256, 1024);
    alpha_k<<<ceildiv(N * 6, 4), 256, 0, stream>>>(hbuf, a3s, a3d, asrc, adst, N, 6);
    gat_agg_mean<<<ceildiv(N, 4), 256, 0, stream>>>(hbuf, asrc, adst, row_off, csr_src,
                                                    out, N);
}

// Round 5
// 489.861 us; speedup vs baseline: 4.0794x; 1.1401x over previous
//
#include <hip/hip_runtime.h>
#include <hip/hip_bf16.h>
#include <cstddef>

#define NN 10000      // nodes
#define EE0 160000    // raw edges (self-loops added on top)
#define NF 14
#define DC 256        // per-head channels

static inline int ceildiv(int a, int b) { return (a + b - 1) / b; }

__device__ __forceinline__ float lrelu02(float x) { return fmaxf(x, 0.2f * x); }

// round-to-nearest-even fp32 -> bf16 (as raw short)
__device__ __forceinline__ short f2bf(float f) {
    unsigned u = __float_as_uint(f);
    unsigned r = (u + 0x7FFFu + ((u >> 16) & 1u)) >> 16;
    return (short)r;
}
__device__ __forceinline__ float bf2f(short s) {
    return __uint_as_float(((unsigned)(unsigned short)s) << 16);
}

typedef __attribute__((ext_vector_type(8))) short bf16x8;
typedef __attribute__((ext_vector_type(4))) float f32x4;

#define GLDS(gaddr, laddr)                                                         \
    __builtin_amdgcn_global_load_lds(                                              \
        (__attribute__((address_space(1))) void*)(gaddr),                          \
        (__attribute__((address_space(3))) void*)(laddr), 16, 0, 0)

// ---------------- CSR build ----------------
__global__ void count_edges_k(const int* __restrict__ ei, int* __restrict__ counts,
                              int E0, int N) {
    int e = blockIdx.x * 256 + threadIdx.x;
    int E = E0 + N;
    if (e >= E) return;
    int dst = (e < E0) ? ei[E0 + e] : (e - E0);
    atomicAdd(&counts[dst], 1);
}

// 1024 threads; each scans a contiguous chunk; one 1024-wide LDS scan (10 steps).
__global__ __launch_bounds__(1024) void scan_k(const int* __restrict__ counts,
                                               int* __restrict__ row_off, int n) {
    __shared__ int sums[1024];
    int t = threadIdx.x;
    int chunk = (n + 1023) >> 10;
    int base = t * chunk;
    int lim = base + chunk; if (lim > n) lim = n;
    int s = 0;
    for (int i = base; i < lim; ++i) s += counts[i];
    sums[t] = s;
    __syncthreads();
    for (int off = 1; off < 1024; off <<= 1) {
        int v = (t >= off) ? sums[t - off] : 0;
        __syncthreads();
        sums[t] += v;
        __syncthreads();
    }
    int run = (t == 0) ? 0 : sums[t - 1];   // exclusive prefix of this chunk
    for (int i = base; i < lim; ++i) { run += counts[i]; row_off[i + 1] = run; }
    if (t == 0) row_off[0] = 0;
}

__global__ void scatter_k(const int* __restrict__ ei, const int* __restrict__ row_off,
                          int* __restrict__ cursor, int* __restrict__ csr_src,
                          int E0, int N) {
    int e = blockIdx.x * 256 + threadIdx.x;
    int E = E0 + N;
    if (e >= E) return;
    int src, dst;
    if (e < E0) { src = ei[e]; dst = ei[E0 + e]; }
    else        { src = dst = e - E0; }
    int pos = row_off[dst] + atomicAdd(&cursor[dst], 1);
    csr_src[pos] = src;
}

// ---------------- fused fp32 -> bf16 weight conversion (4 segments) ----------------
__global__ __launch_bounds__(256) void cvt_bf16_fused_k(
    const float* __restrict__ p0, short* __restrict__ q0, int n0,
    const float* __restrict__ p1, short* __restrict__ q1, int n1,
    const float* __restrict__ p2, short* __restrict__ q2, int n2,
    const float* __restrict__ p3, short* __restrict__ q3, int n3) {
    int i = blockIdx.x * 256 + threadIdx.x;
    const float* in; short* out; int idx;
    if (i < n0) { in = p0; out = q0; idx = i; }
    else if (i < n0 + n1) { in = p1; out = q1; idx = i - n0; }
    else if (i < n0 + n1 + n2) { in = p2; out = q2; idx = i - n0 - n1; }
    else if (i < n0 + n1 + n2 + n3) { in = p3; out = q3; idx = i - n0 - n1 - n2; }
    else return;
    float4 v = ((const float4*)in)[idx];
    short4 o;
    o.x = f2bf(v.x); o.y = f2bf(v.y); o.z = f2bf(v.z); o.w = f2bf(v.w);
    ((short4*)out)[idx] = o;
}

// ---------------- K-pad fp32 [rows,K] -> bf16 [rows,Kp] (zero tail), 3 segments ----
__global__ __launch_bounds__(256) void pad_bf16_k(
    const float* __restrict__ p0, short* __restrict__ q0, int r0,
    const float* __restrict__ p1, short* __restrict__ q1, int r1,
    const float* __restrict__ p2, short* __restrict__ q2, int r2,
    int K, int Kp) {
    int i = blockIdx.x * 256 + threadIdx.x;
    int rows = r0 + r1 + r2;
    int total = rows * Kp;
    if (i >= total) return;
    int row = i / Kp, col = i - row * Kp;
    const float* in; short* out; int r;
    if (row < r0) { in = p0; out = q0; r = row; }
    else if (row < r0 + r1) { in = p1; out = q1; r = row - r0; }
    else { in = p2; out = q2; r = row - r0 - r1; }
    out[(size_t)r * Kp + col] = (col < K) ? f2bf(in[(size_t)r * K + col]) : (short)0;
}

// ---------------- dual-output bf16 MFMA GEMM ----------------
// B has Nh+Nf rows (concat). cols [0,Nh) -> Cb bf16 (stride Nh, no bias);
// cols [Nh,Nh+Nf) -> Cf fp32 (stride Nf, + b1+b2). N-blocks are 128-aligned
// within a single region. A,B bf16 K-contiguous, K%32==0, M tail clamped.
__global__ __launch_bounds__(256) void gemm_bf16_dual(
    const short* __restrict__ A, const short* __restrict__ B,
    const float* __restrict__ b1, const float* __restrict__ b2,
    short* __restrict__ Cb, float* __restrict__ Cf,
    int M, int Nh, int Nf, int K) {
    __shared__ short As[128 * 32];
    __shared__ short Bs[128 * 32];
    const int t = threadIdx.x;
    const int wave = t >> 6, lane = t & 63;
    const int m0 = blockIdx.y * 128, n0 = blockIdx.x * 128;
    const int wm = (wave >> 1) * 64, wn = (wave & 1) * 64;
    const int lane15 = lane & 15, quad = lane >> 4;

    const int lrow = lane >> 2;        // row within wave region
    const int lk = (lane & 3) * 8;     // k offset in shorts (16B chunks)
    int arow0 = m0 + wave * 16 + lrow;
    int arow1 = arow0 + 64;
    if (arow0 > M - 1) arow0 = M - 1;
    if (arow1 > M - 1) arow1 = M - 1;
    const short* ag0 = A + (size_t)arow0 * K + lk;
    const short* ag1 = A + (size_t)arow1 * K + lk;
    const short* bg0 = B + (size_t)(n0 + wave * 16 + lrow) * K + lk;
    const short* bg1 = B + (size_t)(n0 + 64 + wave * 16 + lrow) * K + lk;
    short* al0 = &As[(wave * 16) * 32];
    short* al1 = &As[(64 + wave * 16) * 32];
    short* bl0 = &Bs[(wave * 16) * 32];
    short* bl1 = &Bs[(64 + wave * 16) * 32];

    f32x4 acc[4][4];
#pragma unroll
    for (int i = 0; i < 4; ++i)
#pragma unroll
        for (int j = 0; j < 4; ++j) acc[i][j] = (f32x4){0.f, 0.f, 0.f, 0.f};

    for (int k0 = 0; k0 < K; k0 += 32) {
        GLDS(ag0 + k0, al0);
        GLDS(ag1 + k0, al1);
        GLDS(bg0 + k0, bl0);
        GLDS(bg1 + k0, bl1);
        __syncthreads();
        bf16x8 af[4], bfr[4];
#pragma unroll
        for (int i = 0; i < 4; ++i)
            af[i] = *(const bf16x8*)&As[(wm + 16 * i + lane15) * 32 + quad * 8];
#pragma unroll
        for (int j = 0; j < 4; ++j)
            bfr[j] = *(const bf16x8*)&Bs[(wn + 16 * j + lane15) * 32 + quad * 8];
#pragma unroll
        for (int i = 0; i < 4; ++i)
#pragma unroll
            for (int j = 0; j < 4; ++j)
                acc[i][j] = __builtin_amdgcn_mfma_f32_16x16x32_bf16(
                    af[i], bfr[j], acc[i][j], 0, 0, 0);
        __syncthreads();
    }

    if (n0 >= Nh) {
        // fp32 + bias region
#pragma unroll
        for (int j = 0; j < 4; ++j) {
            int nc = n0 - Nh + wn + 16 * j + lane15;
            float bias = b1[nc] + b2[nc];
#pragma unroll
            for (int i = 0; i < 4; ++i) {
                int mb = m0 + wm + 16 * i + quad * 4;
#pragma unroll
                for (int r = 0; r < 4; ++r) {
                    int m = mb + r;
                    if (m < M) Cf[(size_t)m * Nf + nc] = acc[i][j][r] + bias;
                }
            }
        }
    } else {
        // bf16 region (h)
#pragma unroll
        for (int j = 0; j < 4; ++j) {
            int n = n0 + wn + 16 * j + lane15;
#pragma unroll
            for (int i = 0; i < 4; ++i) {
                int mb = m0 + wm + 16 * i + quad * 4;
#pragma unroll
                for (int r = 0; r < 4; ++r) {
                    int m = mb + r;
                    if (m < M) Cb[(size_t)m * Nh + n] = f2bf(acc[i][j][r]);
                }
            }
        }
    }
}

// ---------------- alpha_src/alpha_dst: [N,H] dot over C=256, bf16 h ----------------
__global__ __launch_bounds__(256) void alpha_k(
    const short* __restrict__ h, const float* __restrict__ a_s,
    const float* __restrict__ a_d, float* __restrict__ asrc,
    float* __restrict__ adst, int N, int H) {
    int wid = (int)((blockIdx.x * (size_t)blockDim.x + threadIdx.x) >> 6);
    int lane = threadIdx.x & 63;
    if (wid >= N * H) return;
    int n = wid / H, hh = wid - n * H;
    const short4 hv4 = *(const short4*)(h + (size_t)n * H * DC + hh * DC + lane * 4);
    const float4 sv = *(const float4*)(a_s + hh * DC + lane * 4);
    const float4 dv = *(const float4*)(a_d + hh * DC + lane * 4);
    float hx = bf2f(hv4.x), hy = bf2f(hv4.y), hz = bf2f(hv4.z), hw = bf2f(hv4.w);
    float s = hx * sv.x + hy * sv.y + hz * sv.z + hw * sv.w;
    float d = hx * dv.x + hy * dv.y + hz * dv.z + hw * dv.w;
#pragma unroll
    for (int off = 32; off > 0; off >>= 1) {
        s += __shfl_down(s, off);
        d += __shfl_down(d, off);
    }
    if (lane == 0) { asrc[wid] = s; adst[wid] = d; }
}

// ---------------- GAT aggregation, concat heads, fused lin-skip + ELU, bf16 out ----
// one wave per (node, head); fast path deg<=64 keeps edges in registers;
// edge loop unrolled x4 for load-level parallelism.
__global__ __launch_bounds__(256) void gat_agg(
    const short* __restrict__ hbuf, const float* __restrict__ lin,
    const float* __restrict__ asrc, const float* __restrict__ adst_a,
    const int* __restrict__ row_off, const int* __restrict__ csr_src,
    short* __restrict__ outx, int N, int H) {
    int wid = (int)((blockIdx.x * (size_t)blockDim.x + threadIdx.x) >> 6);
    int lane = threadIdx.x & 63;
    if (wid >= N * H) return;
    int n = wid / H, hh = wid - n * H;
    int beg = row_off[n], end = row_off[n + 1];
    int deg = end - beg;
    float ad = adst_a[wid];

    size_t cbase = (size_t)n * H * DC + hh * DC + lane * 4;
    float4 acc = *(const float4*)(lin + cbase);

    if (deg <= 64) {
        int s = 0; float e = -1e38f;
        if (lane < deg) {
            s = csr_src[beg + lane];
            e = lrelu02(asrc[s * H + hh] + ad);
        }
        float m = e;
#pragma unroll
        for (int off = 32; off > 0; off >>= 1) m = fmaxf(m, __shfl_xor(m, off));
        float p = (lane < deg) ? __expf(e - m) : 0.f;
        float dsum = p;
#pragma unroll
        for (int off = 32; off > 0; off >>= 1) dsum += __shfl_xor(dsum, off);
        float coef = p / (dsum + 1e-16f);

        const size_t hoff = (size_t)hh * DC + lane * 4;
        int i = 0;
        for (; i + 4 <= deg; i += 4) {
            int s0 = __shfl(s, i), s1 = __shfl(s, i + 1);
            int s2 = __shfl(s, i + 2), s3 = __shfl(s, i + 3);
            const short4 v0 = *(const short4*)(hbuf + (size_t)s0 * (H * DC) + hoff);
            const short4 v1 = *(const short4*)(hbuf + (size_t)s1 * (H * DC) + hoff);
            const short4 v2 = *(const short4*)(hbuf + (size_t)s2 * (H * DC) + hoff);
            const short4 v3 = *(const short4*)(hbuf + (size_t)s3 * (H * DC) + hoff);
            float w0 = __shfl(coef, i), w1 = __shfl(coef, i + 1);
            float w2 = __shfl(coef, i + 2), w3 = __shfl(coef, i + 3);
            acc.x += w0 * bf2f(v0.x) + w1 * bf2f(v1.x) + w2 * bf2f(v2.x) + w3 * bf2f(v3.x);
            acc.y += w0 * bf2f(v0.y) + w1 * bf2f(v1.y) + w2 * bf2f(v2.y) + w3 * bf2f(v3.y);
            acc.z += w0 * bf2f(v0.z) + w1 * bf2f(v1.z) + w2 * bf2f(v2.z) + w3 * bf2f(v3.z);
            acc.w += w0 * bf2f(v0.w) + w1 * bf2f(v1.w) + w2 * bf2f(v2.w) + w3 * bf2f(v3.w);
        }
        for (; i < deg; ++i) {
            float wv = __shfl(coef, i);
            int si = __shfl(s, i);
            const short4 hv = *(const short4*)(hbuf + (size_t)si * (H * DC) + hoff);
            acc.x += wv * bf2f(hv.x); acc.y += wv * bf2f(hv.y);
            acc.z += wv * bf2f(hv.z); acc.w += wv * bf2f(hv.w);
        }
    } else {
        float m = -1e38f;
        for (int i = beg + lane; i < end; i += 64) {
            int s = csr_src[i];
            m = fmaxf(m, lrelu02(asrc[s * H + hh] + ad));
        }
#pragma unroll
        for (int off = 32; off > 0; off >>= 1) m = fmaxf(m, __shfl_xor(m, off));
        float dsum = 0.f;
        for (int i = beg + lane; i < end; i += 64) {
            int s = csr_src[i];
            dsum += __expf(lrelu02(asrc[s * H + hh] + ad) - m);
        }
#pragma unroll
        for (int off = 32; off > 0; off >>= 1) dsum += __shfl_xor(dsum, off);
        float inv = 1.f / (dsum + 1e-16f);
        for (int i = beg; i < end; ++i) {
            int s = csr_src[i];
            float wv = __expf(lrelu02(asrc[s * H + hh] + ad) - m) * inv;
            const short4 hv = *(const short4*)(hbuf + ((size_t)s * H + hh) * DC + lane * 4);
            acc.x += wv * bf2f(hv.x); acc.y += wv * bf2f(hv.y);
            acc.z += wv * bf2f(hv.z); acc.w += wv * bf2f(hv.w);
        }
    }
    // ELU + bf16
    acc.x = acc.x > 0.f ? acc.x : __expf(acc.x) - 1.f;
    acc.y = acc.y > 0.f ? acc.y : __expf(acc.y) - 1.f;
    acc.z = acc.z > 0.f ? acc.z : __expf(acc.z) - 1.f;
    acc.w = acc.w > 0.f ? acc.w : __expf(acc.w) - 1.f;
    short4 o;
    o.x = f2bf(acc.x); o.y = f2bf(acc.y); o.z = f2bf(acc.z); o.w = f2bf(acc.w);
    *(short4*)(outx + cbase) = o;
}

// ---------------- Layer-3 aggregation: mean over 6 heads, write d_out[N,256] -------
// one wave per node; edge loop unrolled x2 (12 gathers in flight).
__global__ __launch_bounds__(256) void gat_agg_mean(
    const short* __restrict__ hbuf, const float* __restrict__ asrc,
    const float* __restrict__ adst_a, const int* __restrict__ row_off,
    const int* __restrict__ csr_src, float* __restrict__ out, int N) {
    const int H = 6;
    int wid = (int)((blockIdx.x * (size_t)blockDim.x + threadIdx.x) >> 6);
    int lane = threadIdx.x & 63;
    if (wid >= N) return;
    int n = wid;
    int beg = row_off[n], end = row_off[n + 1];
    int deg = end - beg;
    const float invH = 1.f / 6.f;

    float4 acc = *(const float4*)(out + (size_t)n * DC + lane * 4);

    if (deg <= 64) {
        int s = 0;
        float as6[6];
        if (lane < deg) {
            s = csr_src[beg + lane];
            const float2* ap = (const float2*)(asrc + (size_t)s * H);
            float2 v0 = ap[0], v1 = ap[1], v2 = ap[2];
            as6[0] = v0.x; as6[1] = v0.y; as6[2] = v1.x;
            as6[3] = v1.y; as6[4] = v2.x; as6[5] = v2.y;
        }
        float coefh[6];
#pragma unroll
        for (int hh = 0; hh < 6; ++hh) {
            float ad = adst_a[n * H + hh];
            float e = (lane < deg) ? lrelu02(as6[hh] + ad) : -1e38f;
            float m = e;
#pragma unroll
            for (int off = 32; off > 0; off >>= 1) m = fmaxf(m, __shfl_xor(m, off));
            float p = (lane < deg) ? __expf(e - m) : 0.f;
            float dsum = p;
#pragma unroll
            for (int off = 32; off > 0; off >>= 1) dsum += __shfl_xor(dsum, off);
            coefh[hh] = p * invH / (dsum + 1e-16f);
        }
        int i = 0;
        for (; i + 2 <= deg; i += 2) {
            int sa = __shfl(s, i), sb = __shfl(s, i + 1);
            const short* ha = hbuf + (size_t)sa * (H * DC) + lane * 4;
            const short* hb = hbuf + (size_t)sb * (H * DC) + lane * 4;
            short4 va[6], vb[6];
#pragma unroll
            for (int hh = 0; hh < 6; ++hh) {
                va[hh] = *(const short4*)(ha + hh * DC);
                vb[hh] = *(const short4*)(hb + hh * DC);
            }
#pragma unroll
            for (int hh = 0; hh < 6; ++hh) {
                float wa = __shfl(coefh[hh], i), wb = __shfl(coefh[hh], i + 1);
                acc.x += wa * bf2f(va[hh].x) + wb * bf2f(vb[hh].x);
                acc.y += wa * bf2f(va[hh].y) + wb * bf2f(vb[hh].y);
                acc.z += wa * bf2f(va[hh].z) + wb * bf2f(vb[hh].z);
                acc.w += wa * bf2f(va[hh].w) + wb * bf2f(vb[hh].w);
            }
        }
        if (i < deg) {
            int si = __shfl(s, i);
            const short* hb = hbuf + (size_t)si * (H * DC) + lane * 4;
#pragma unroll
            for (int hh = 0; hh < 6; ++hh) {
                float wv = __shfl(coefh[hh], i);
                const short4 hv = *(const short4*)(hb + hh * DC);
                acc.x += wv * bf2f(hv.x); acc.y += wv * bf2f(hv.y);
                acc.z += wv * bf2f(hv.z); acc.w += wv * bf2f(hv.w);
            }
        }
    } else {
        for (int hh = 0; hh < 6; ++hh) {
            float ad = adst_a[n * H + hh];
            float m = -1e38f;
            for (int i = beg + lane; i < end; i += 64) {
                int s = csr_src[i];
                m = fmaxf(m, lrelu02(asrc[s * H + hh] + ad));
            }
#pragma unroll
            for (int off = 32; off > 0; off >>= 1) m = fmaxf(m, __shfl_xor(m, off));
            float dsum = 0.f;
            for (int i = beg + lane; i < end; i += 64) {
                int s = csr_src[i];
                dsum += __expf(lrelu02(asrc[s * H + hh] + ad) - m);
            }
#pragma unroll
            for (int off = 32; off > 0; off >>= 1) dsum += __shfl_xor(dsum, off);
            float inv = invH / (dsum + 1e-16f);
            for (int i = beg; i < end; ++i) {
                int s = csr_src[i];
                float wv = __expf(lrelu02(asrc[s * H + hh] + ad) - m) * inv;
                const short4 hv =
                    *(const short4*)(hbuf + (size_t)s * (H * DC) + hh * DC + lane * 4);
                acc.x += wv * bf2f(hv.x); acc.y += wv * bf2f(hv.y);
                acc.z += wv * bf2f(hv.z); acc.w += wv * bf2f(hv.w);
            }
        }
    }
    *(float4*)(out + (size_t)n * DC + lane * 4) = acc;
}

// ---------------- launch ----------------
extern "C" void kernel_launch(void* const* d_in, const int* in_sizes, int n_in,
                              void* d_out, int out_size, void* d_ws, size_t ws_size,
                              hipStream_t stream) {
    const float* x   = (const float*)d_in[0];
    const int*   ei  = (const int*)d_in[1];
    const float* W1  = (const float*)d_in[2];
    const float* a1s = (const float*)d_in[3];
    const float* a1d = (const float*)d_in[4];
    const float* b1  = (const float*)d_in[5];
    const float* lw1 = (const float*)d_in[6];
    const float* lb1 = (const float*)d_in[7];
    const float* W2  = (const float*)d_in[8];
    const float* a2s = (const float*)d_in[9];
    const float* a2d = (const float*)d_in[10];
    const float* b2  = (const float*)d_in[11];
    const float* lw2 = (const float*)d_in[12];
    const float* lb2 = (const float*)d_in[13];
    const float* W3  = (const float*)d_in[14];
    const float* a3s = (const float*)d_in[15];
    const float* a3d = (const float*)d_in[16];
    const float* b3  = (const float*)d_in[17];
    const float* lw3 = (const float*)d_in[18];
    const float* lb3 = (const float*)d_in[19];
    float* out = (float*)d_out;

    const int N = NN, E0 = EE0, E = EE0 + NN;

    unsigned char* w = (unsigned char*)d_ws;
    size_t off = 0;
    auto alloc = [&](size_t bytes) {
        void* p = w + off;
        off += (bytes + 255) & ~(size_t)255;
        return p;
    };
    short* hbuf   = (short*)alloc((size_t)N * 1536 * 2);  // h bf16 (max: layer 3)
    float* buf    = (float*)alloc((size_t)N * 1024 * 4);  // lin1, then lin2 (fp32)
    short* xb     = (short*)alloc((size_t)N * 1024 * 2);  // x1 bf16, then x2 bf16
    short* xpad   = (short*)alloc((size_t)N * 32 * 2);    // x zero-padded K=32 bf16
    // B-concat pairs: each region is a 256-multiple so pairs stay contiguous
    short* W1p    = (short*)alloc((size_t)1024 * 32 * 2);       // + lw1p right after
    short* lw1p   = (short*)alloc((size_t)1024 * 32 * 2);
    short* W2b    = (short*)alloc((size_t)1024 * 1024 * 2);     // + lw2b right after
    short* lw2b   = (short*)alloc((size_t)1024 * 1024 * 2);
    short* W3b    = (short*)alloc((size_t)1536 * 1024 * 2);     // + lw3b right after
    short* lw3b   = (short*)alloc((size_t)256 * 1024 * 2);
    float* asrc   = (float*)alloc((size_t)N * 6 * 4);
    float* adst   = (float*)alloc((size_t)N * 6 * 4);
    int* row_off  = (int*)alloc((size_t)(N + 1) * 4);
    int* counts2  = (int*)alloc((size_t)2 * N * 4);  // counts | cursor
    int* counts   = counts2;
    int* cursor   = counts2 + N;
    int* csr_src  = (int*)alloc((size_t)E * 4);
    (void)ws_size; (void)n_in; (void)in_sizes; (void)out_size;

    // ---- CSR build ----
    hipMemsetAsync(counts2, 0, (size_t)2 * N * 4, stream);
    count_edges_k<<<ceildiv(E, 256), 256, 0, stream>>>(ei, counts, E0, N);
    scan_k<<<1, 1024, 0, stream>>>(counts, row_off, N);
    scatter_k<<<ceildiv(E, 256), 256, 0, stream>>>(ei, row_off, cursor, csr_src, E0, N);

    // ---- weight bf16 conversion (fused) + K-pad for layer 1 ----
    {
        int q0 = 1024 * 1024 / 4, q1 = 1024 * 1024 / 4, q2 = 1536 * 1024 / 4,
            q3 = 256 * 1024 / 4;
        cvt_bf16_fused_k<<<ceildiv(q0 + q1 + q2 + q3, 256), 256, 0, stream>>>(
            W2, W2b, q0, lw2, lw2b, q1, W3, W3b, q2, lw3, lw3b, q3);
        int rows = N + 1024 + 1024;
        pad_bf16_k<<<ceildiv(rows * 32, 256), 256, 0, stream>>>(
            x, xpad, N, W1, W1p, 1024, lw1, lw1p, 1024, NF, 32);
    }

    // ---- Layer 1 (H=4, K=14 padded to 32): h->hbuf bf16, lin->buf fp32 ----
    gemm_bf16_dual<<<dim3(16, ceildiv(N, 128)), 256, 0, stream>>>(
        xpad, W1p, b1, lb1, hbuf, buf, N, 1024, 1024, 32);
    alpha_k<<<ceildiv(N * 4, 4), 256, 0, stream>>>(hbuf, a1s, a1d, asrc, adst, N, 4);
    gat_agg<<<ceildiv(N * 4, 4), 256, 0, stream>>>(hbuf, buf, asrc, adst, row_off, csr_src,
                                                   xb, N, 4);

    // ---- Layer 2 (H=4, K=1024) ----
    gemm_bf16_dual<<<dim3(16, ceildiv(N, 128)), 256, 0, stream>>>(
        xb, W2b, b2, lb2, hbuf, buf, N, 1024, 1024, 1024);
    alpha_k<<<ceildiv(N * 4, 4), 256, 0, stream>>>(hbuf, a2s, a2d, asrc, adst, N, 4);
    gat_agg<<<ceildiv(N * 4, 4), 256, 0, stream>>>(hbuf, buf, asrc, adst, row_off, csr_src,
                                                   xb, N, 4);

    // ---- Layer 3 (H=6, K=1024, mean heads): h->hbuf, lin->out fp32 ----
    gemm_bf16_dual<<<dim3(14, ceildiv(N, 128)), 256, 0, stream>>>(
        xb, W3b, b3, lb3, hbuf, out, N, 1536, 256, 1024);
    alpha_k<<<ceildiv(N * 6, 4), 256, 0, stream>>>(hbuf, a3s, a3d, asrc, adst, N, 6);
    gat_agg_mean<<<ceildiv(N, 4), 256, 0, stream>>>(hbuf, asrc, adst, row_off, csr_src,
                                                    out, N);
}